// Round 12
// baseline (393.086 us; speedup 1.0000x reference)
//
#include <hip/hip_runtime.h>

#define DIN 256
#define HD 64
#define NHEAD 4

static inline int cdiv(long a, long b) { return (int)((a + b - 1) / b); }

typedef __attribute__((ext_vector_type(8))) short bf16x8;
typedef __attribute__((ext_vector_type(4))) float f32x4;

// ---------------- CSR build ----------------
__global__ __launch_bounds__(256) void k_count(const int* __restrict__ dst,
                                               int* __restrict__ cnt, int E) {
  int i = blockIdx.x * 256 + threadIdx.x;
  if (i < E) atomicAdd(&cnt[dst[i]], 1);
}

// block sums of (cnt+1)
__global__ __launch_bounds__(256) void k_bsum(const int* __restrict__ cnt,
                                              int* __restrict__ bsum, int n) {
  __shared__ int sd[256];
  int i = blockIdx.x * 256 + threadIdx.x;
  sd[threadIdx.x] = (i < n) ? cnt[i] + 1 : 0;
  __syncthreads();
  for (int o = 128; o > 0; o >>= 1) {
    if (threadIdx.x < o) sd[threadIdx.x] += sd[threadIdx.x + o];
    __syncthreads();
  }
  if (threadIdx.x == 0) bsum[blockIdx.x] = sd[0];
}

// rowptr (scans bsum inline) + cursor + dinv + GSUM zero
__global__ __launch_bounds__(256) void k_rowptr(const int* __restrict__ cnt,
                                                const int* __restrict__ bsum,
                                                int* __restrict__ row_ptr,
                                                int* __restrict__ cursor,
                                                float* __restrict__ dinv,
                                                float* __restrict__ gsum,
                                                int n, int total, int B) {
  __shared__ int sb[256];
  __shared__ int sd[256];
  int t = threadIdx.x;
  sb[t] = (t < B) ? bsum[t] : 0;
  __syncthreads();
  for (int o = 1; o < 256; o <<= 1) {
    int x = (t >= o) ? sb[t - o] : 0;
    __syncthreads();
    sb[t] += x;
    __syncthreads();
  }
  int boff = (blockIdx.x > 0) ? sb[blockIdx.x - 1] : 0;
  int i = blockIdx.x * 256 + t;
  int v = (i < n) ? cnt[i] + 1 : 0;
  sd[t] = v;
  __syncthreads();
  for (int o = 1; o < 256; o <<= 1) {
    int x = (t >= o) ? sd[t - o] : 0;
    __syncthreads();
    sd[t] += x;
    __syncthreads();
  }
  if (i < n) {
    int rp = boff + sd[t] - v;
    row_ptr[i] = rp;
    cursor[i] = rp;
    dinv[i] = rsqrtf((float)v);
  }
  if (i == n - 1) row_ptr[n] = total;
  if (blockIdx.x == 0 && t < 64) gsum[t] = 0.f;
}

__global__ __launch_bounds__(256) void k_csrfill(const int* __restrict__ src,
                                                 const int* __restrict__ dst,
                                                 int* __restrict__ cursor,
                                                 int* __restrict__ csr_src, int E, int n) {
  int e = blockIdx.x * 256 + threadIdx.x;
  if (e < E) {
    int pos = atomicAdd(&cursor[dst[e]], 1);
    csr_src[pos] = src[e];
  } else if (e < E + n) {
    int i = e - E;
    int pos = atomicAdd(&cursor[i], 1);
    csr_src[pos] = i;
  }
}

// ---------------- bf16 helpers ----------------
__device__ __forceinline__ unsigned short f2bf(float f) {  // RNE
  unsigned u = __float_as_uint(f);
  u += 0x7FFFu + ((u >> 16) & 1u);
  return (unsigned short)(u >> 16);
}
__device__ __forceinline__ float bflo(unsigned u) { return __uint_as_float(u << 16); }
__device__ __forceinline__ float bfhi(unsigned u) { return __uint_as_float(u & 0xFFFF0000u); }

// ---------------- MFMA GEMM (x@W0 only): c16[n,64](bf16) = A[n,256] @ W[256,64] ----------------
__global__ __launch_bounds__(256, 4) void k_gmfma0(const float* __restrict__ A,
                                                   const float* __restrict__ W,
                                                   unsigned short* __restrict__ c16, int n) {
  __shared__ unsigned short As[64][64];
  __shared__ unsigned short Wt[64][64];
  const int tid = threadIdx.x;
  const int m0 = blockIdx.x * 64;
  const int lane = tid & 63;
  const int wid = tid >> 6;
  const int wm = wid * 16;
  const int fr = lane & 15;
  const int fg = lane >> 4;
  f32x4 acc[4] = {{0.f, 0.f, 0.f, 0.f},
                  {0.f, 0.f, 0.f, 0.f},
                  {0.f, 0.f, 0.f, 0.f},
                  {0.f, 0.f, 0.f, 0.f}};

  for (int k0 = 0; k0 < 256; k0 += 64) {
    {
      int row = tid >> 3;  // 0..31
      int g = tid & 7;
#pragma unroll
      for (int q = 0; q < 2; ++q, row += 32) {
        int gr = m0 + row;
        gr = gr < n ? gr : n - 1;
        const float* ap = A + (size_t)gr * 256 + k0 + g * 8;
        float4 f0 = *(const float4*)ap;
        float4 f1 = *(const float4*)(ap + 4);
        uint4 pk;
        pk.x = (unsigned)f2bf(f0.x) | ((unsigned)f2bf(f0.y) << 16);
        pk.y = (unsigned)f2bf(f0.z) | ((unsigned)f2bf(f0.w) << 16);
        pk.z = (unsigned)f2bf(f1.x) | ((unsigned)f2bf(f1.y) << 16);
        pk.w = (unsigned)f2bf(f1.z) | ((unsigned)f2bf(f1.w) << 16);
        *(uint4*)&As[row][(g ^ (row & 7)) * 8] = pk;
      }
    }
    {
      int col = tid & 63;
      int kb = (tid >> 6) * 16;
      unsigned pk[8];
#pragma unroll
      for (int i = 0; i < 8; ++i) {
        float lo = W[(size_t)(k0 + kb + 2 * i) * HD + col];
        float hi = W[(size_t)(k0 + kb + 2 * i + 1) * HD + col];
        pk[i] = (unsigned)f2bf(lo) | ((unsigned)f2bf(hi) << 16);
      }
      int g0 = kb >> 3;
      uint4 w0; w0.x = pk[0]; w0.y = pk[1]; w0.z = pk[2]; w0.w = pk[3];
      uint4 w1; w1.x = pk[4]; w1.y = pk[5]; w1.z = pk[6]; w1.w = pk[7];
      *(uint4*)&Wt[col][((g0) ^ (col & 7)) * 8] = w0;
      *(uint4*)&Wt[col][((g0 + 1) ^ (col & 7)) * 8] = w1;
    }
    __syncthreads();
#pragma unroll
    for (int ks = 0; ks < 2; ++ks) {
      int ga = ks * 4 + fg;
      bf16x8 af = *(const bf16x8*)&As[wm + fr][(ga ^ (fr & 7)) * 8];
#pragma unroll
      for (int nt = 0; nt < 4; ++nt) {
        bf16x8 bfr = *(const bf16x8*)&Wt[nt * 16 + fr][(ga ^ (fr & 7)) * 8];
        acc[nt] = __builtin_amdgcn_mfma_f32_16x16x32_bf16(af, bfr, acc[nt], 0, 0, 0);
      }
    }
    __syncthreads();
  }

#pragma unroll
  for (int nt = 0; nt < 4; ++nt) {
#pragma unroll
    for (int r = 0; r < 4; ++r) {
      int row = m0 + wm + fg * 4 + r;
      if (row < n) c16[(size_t)row * HD + nt * 16 + fr] = f2bf(acc[nt][r]);
    }
  }
}

// ---------------- fused GCN layer: gather(P16in) -> h (LDS bf16) -> GEMM W -> c16 ----------------
// RESID: add hin; WRITE_H: store f32 h to hout; WG: W is [64][256] (4 col groups) + att dots
template <int RESID, int WRITE_H, int WG>
__global__ __launch_bounds__(256, 4) void k_layer(const unsigned short* __restrict__ Pin,
                                                  const int* __restrict__ csr_src,
                                                  const int* __restrict__ row_ptr,
                                                  const float* __restrict__ dinv,
                                                  const float* __restrict__ bias,
                                                  const float* __restrict__ hin,
                                                  float* __restrict__ hout,
                                                  const float* __restrict__ W,
                                                  unsigned short* __restrict__ c16,
                                                  const float* __restrict__ attS,
                                                  const float* __restrict__ attD,
                                                  float* __restrict__ a_s,
                                                  float* __restrict__ a_d, int n) {
  __shared__ unsigned short As[64][64];
  __shared__ unsigned short Ws[64][64];
  const int tid = threadIdx.x, lane = tid & 63, wid = tid >> 6;
  const int m0 = blockIdx.x * 64;
  const int es = lane >> 3, fo = (lane & 7) * 8;

  // ---- phase 1: gather, 16 nodes per wave ----
  for (int j = 0; j < 16; ++j) {
    int row = wid * 16 + j;
    int node = m0 + row;
    float a[8] = {};
    if (node < n) {
      int beg = row_ptr[node], end = row_ptr[node + 1];
      for (int i = beg + es; i < end; i += 8) {
        int s = csr_src[i];  // uniform within eighth
        float d = dinv[s];
        uint4 v = *(const uint4*)(Pin + (size_t)s * HD + fo);
        a[0] = fmaf(bflo(v.x), d, a[0]); a[1] = fmaf(bfhi(v.x), d, a[1]);
        a[2] = fmaf(bflo(v.y), d, a[2]); a[3] = fmaf(bfhi(v.y), d, a[3]);
        a[4] = fmaf(bflo(v.z), d, a[4]); a[5] = fmaf(bfhi(v.z), d, a[5]);
        a[6] = fmaf(bflo(v.w), d, a[6]); a[7] = fmaf(bfhi(v.w), d, a[7]);
      }
    }
#pragma unroll
    for (int o = 8; o < 64; o <<= 1) {
#pragma unroll
      for (int k = 0; k < 8; ++k) a[k] += __shfl_xor(a[k], o);
    }
    if (lane < 8) {
      if (node < n) {
        float dn = dinv[node];
        float4 b0v = *(const float4*)(bias + fo);
        float4 b1v = *(const float4*)(bias + fo + 4);
        float o0[8];
        o0[0] = a[0] * dn + b0v.x; o0[1] = a[1] * dn + b0v.y;
        o0[2] = a[2] * dn + b0v.z; o0[3] = a[3] * dn + b0v.w;
        o0[4] = a[4] * dn + b1v.x; o0[5] = a[5] * dn + b1v.y;
        o0[6] = a[6] * dn + b1v.z; o0[7] = a[7] * dn + b1v.w;
#pragma unroll
        for (int k = 0; k < 8; ++k) o0[k] = o0[k] > 0.f ? o0[k] : 0.f;
        if (RESID) {
          float4 r0 = *(const float4*)(hin + (size_t)node * HD + fo);
          float4 r1 = *(const float4*)(hin + (size_t)node * HD + fo + 4);
          o0[0] += r0.x; o0[1] += r0.y; o0[2] += r0.z; o0[3] += r0.w;
          o0[4] += r1.x; o0[5] += r1.y; o0[6] += r1.z; o0[7] += r1.w;
        }
        if (WRITE_H) {
          float4 w0; w0.x = o0[0]; w0.y = o0[1]; w0.z = o0[2]; w0.w = o0[3];
          float4 w1; w1.x = o0[4]; w1.y = o0[5]; w1.z = o0[6]; w1.w = o0[7];
          *(float4*)(hout + (size_t)node * HD + fo) = w0;
          *(float4*)(hout + (size_t)node * HD + fo + 4) = w1;
        }
        uint4 pk;
        pk.x = (unsigned)f2bf(o0[0]) | ((unsigned)f2bf(o0[1]) << 16);
        pk.y = (unsigned)f2bf(o0[2]) | ((unsigned)f2bf(o0[3]) << 16);
        pk.z = (unsigned)f2bf(o0[4]) | ((unsigned)f2bf(o0[5]) << 16);
        pk.w = (unsigned)f2bf(o0[6]) | ((unsigned)f2bf(o0[7]) << 16);
        *(uint4*)&As[row][((lane & 7) ^ (row & 7)) * 8] = pk;
      } else {
        uint4 z = {0, 0, 0, 0};
        *(uint4*)&As[row][((lane & 7) ^ (row & 7)) * 8] = z;
      }
    }
  }
  __syncthreads();

  // ---- phase 2: GEMM (h @ W), KIN=64 ----
  const int wm = wid * 16, fr = lane & 15, fg = lane >> 4;
  constexpr int KOUT = WG ? 256 : 64;
  constexpr int NCG = WG ? 4 : 1;
  for (int cg = 0; cg < NCG; ++cg) {
    {
      int col = tid & 63;
      int kb = (tid >> 6) * 16;
      unsigned pk[8];
#pragma unroll
      for (int i = 0; i < 8; ++i) {
        float lo = W[(size_t)(kb + 2 * i) * KOUT + cg * 64 + col];
        float hi = W[(size_t)(kb + 2 * i + 1) * KOUT + cg * 64 + col];
        pk[i] = (unsigned)f2bf(lo) | ((unsigned)f2bf(hi) << 16);
      }
      int g0 = kb >> 3;
      uint4 w0; w0.x = pk[0]; w0.y = pk[1]; w0.z = pk[2]; w0.w = pk[3];
      uint4 w1; w1.x = pk[4]; w1.y = pk[5]; w1.z = pk[6]; w1.w = pk[7];
      *(uint4*)&Ws[col][((g0) ^ (col & 7)) * 8] = w0;
      *(uint4*)&Ws[col][((g0 + 1) ^ (col & 7)) * 8] = w1;
    }
    __syncthreads();
    f32x4 acc[4] = {{0.f, 0.f, 0.f, 0.f}, {0.f, 0.f, 0.f, 0.f},
                    {0.f, 0.f, 0.f, 0.f}, {0.f, 0.f, 0.f, 0.f}};
#pragma unroll
    for (int ks = 0; ks < 2; ++ks) {
      int ga = ks * 4 + fg;
      bf16x8 af = *(const bf16x8*)&As[wm + fr][(ga ^ (fr & 7)) * 8];
#pragma unroll
      for (int nt = 0; nt < 4; ++nt) {
        bf16x8 bfr = *(const bf16x8*)&Ws[nt * 16 + fr][(ga ^ (fr & 7)) * 8];
        acc[nt] = __builtin_amdgcn_mfma_f32_16x16x32_bf16(af, bfr, acc[nt], 0, 0, 0);
      }
    }
#pragma unroll
    for (int nt = 0; nt < 4; ++nt) {
#pragma unroll
      for (int r = 0; r < 4; ++r) {
        int row = m0 + wm + fg * 4 + r;
        if (row < n) c16[(size_t)row * KOUT + cg * 64 + nt * 16 + fr] = f2bf(acc[nt][r]);
      }
    }
    if (WG) {
      float attsv[4], attdv[4];
#pragma unroll
      for (int nt = 0; nt < 4; ++nt) {
        attsv[nt] = attS[cg * 64 + nt * 16 + fr];
        attdv[nt] = attD[cg * 64 + nt * 16 + fr];
      }
#pragma unroll
      for (int r = 0; r < 4; ++r) {
        float ps = acc[0][r] * attsv[0] + acc[1][r] * attsv[1] +
                   acc[2][r] * attsv[2] + acc[3][r] * attsv[3];
        float pd = acc[0][r] * attdv[0] + acc[1][r] * attdv[1] +
                   acc[2][r] * attdv[2] + acc[3][r] * attdv[3];
#pragma unroll
        for (int o = 1; o < 16; o <<= 1) {
          ps += __shfl_xor(ps, o);
          pd += __shfl_xor(pd, o);
        }
        int row = m0 + wm + fg * 4 + r;
        if (fr == 0 && row < n) {
          a_s[row * NHEAD + cg] = ps;
          a_d[row * NHEAD + cg] = pd;
        }
      }
    }
    if (cg + 1 < NCG) __syncthreads();
  }
}

// ---------------- fused rec head: rec = relu(hg@Wr1+br1)@Wr2+br2, + gsum ----------------
__global__ __launch_bounds__(256, 4) void k_rec(const float* __restrict__ hg,
                                                const float* __restrict__ Wr1,
                                                const float* __restrict__ br1,
                                                const float* __restrict__ Wr2,
                                                const float* __restrict__ br2,
                                                float* __restrict__ gsum,
                                                float* __restrict__ rec,
                                                int n) {
  __shared__ unsigned short As[64][64];
  __shared__ unsigned short Ws[64][64];
  __shared__ unsigned short Ts[64][64];
  __shared__ float gs[64];
  const int tid = threadIdx.x;
  const int m0 = blockIdx.x * 64;
  const int lane = tid & 63;
  const int wid = tid >> 6;
  const int wm = wid * 16;
  const int fr = lane & 15, fg = lane >> 4;

  if (tid < 64) gs[tid] = 0.f;
  __syncthreads();

  {
    int row = tid >> 3, g = tid & 7;
#pragma unroll
    for (int q = 0; q < 2; ++q, row += 32) {
      int gr = m0 + row;
      bool valid = gr < n;
      int cr = valid ? gr : n - 1;
      const float* hp = hg + (size_t)cr * HD + g * 8;
      float2 f0 = *(const float2*)hp;
      float2 f1 = *(const float2*)(hp + 2);
      float2 f2 = *(const float2*)(hp + 4);
      float2 f3 = *(const float2*)(hp + 6);
      uint4 pk;
      pk.x = (unsigned)f2bf(f0.x) | ((unsigned)f2bf(f0.y) << 16);
      pk.y = (unsigned)f2bf(f1.x) | ((unsigned)f2bf(f1.y) << 16);
      pk.z = (unsigned)f2bf(f2.x) | ((unsigned)f2bf(f2.y) << 16);
      pk.w = (unsigned)f2bf(f3.x) | ((unsigned)f2bf(f3.y) << 16);
      *(uint4*)&As[row][(g ^ (row & 7)) * 8] = pk;
      if (valid) {
        atomicAdd(&gs[g * 8 + 0], f0.x); atomicAdd(&gs[g * 8 + 1], f0.y);
        atomicAdd(&gs[g * 8 + 2], f1.x); atomicAdd(&gs[g * 8 + 3], f1.y);
        atomicAdd(&gs[g * 8 + 4], f2.x); atomicAdd(&gs[g * 8 + 5], f2.y);
        atomicAdd(&gs[g * 8 + 6], f3.x); atomicAdd(&gs[g * 8 + 7], f3.y);
      }
    }
  }
  {
    int col = tid & 63;
    int kb = (tid >> 6) * 16;
    unsigned pk[8];
#pragma unroll
    for (int i = 0; i < 8; ++i) {
      float lo = Wr1[(size_t)(kb + 2 * i) * HD + col];
      float hi = Wr1[(size_t)(kb + 2 * i + 1) * HD + col];
      pk[i] = (unsigned)f2bf(lo) | ((unsigned)f2bf(hi) << 16);
    }
    int g0 = kb >> 3;
    uint4 w0; w0.x = pk[0]; w0.y = pk[1]; w0.z = pk[2]; w0.w = pk[3];
    uint4 w1; w1.x = pk[4]; w1.y = pk[5]; w1.z = pk[6]; w1.w = pk[7];
    *(uint4*)&Ws[col][((g0) ^ (col & 7)) * 8] = w0;
    *(uint4*)&Ws[col][((g0 + 1) ^ (col & 7)) * 8] = w1;
  }
  __syncthreads();
  if (tid < 64) atomicAdd(&gsum[tid], gs[tid]);

  {
    f32x4 acc[4] = {{0.f, 0.f, 0.f, 0.f}, {0.f, 0.f, 0.f, 0.f},
                    {0.f, 0.f, 0.f, 0.f}, {0.f, 0.f, 0.f, 0.f}};
#pragma unroll
    for (int ks = 0; ks < 2; ++ks) {
      int ga = ks * 4 + fg;
      bf16x8 af = *(const bf16x8*)&As[wm + fr][(ga ^ (fr & 7)) * 8];
#pragma unroll
      for (int nt = 0; nt < 4; ++nt) {
        bf16x8 bfr = *(const bf16x8*)&Ws[nt * 16 + fr][(ga ^ (fr & 7)) * 8];
        acc[nt] = __builtin_amdgcn_mfma_f32_16x16x32_bf16(af, bfr, acc[nt], 0, 0, 0);
      }
    }
#pragma unroll
    for (int nt = 0; nt < 4; ++nt) {
#pragma unroll
      for (int r = 0; r < 4; ++r) {
        int row = wm + fg * 4 + r;
        int col = nt * 16 + fr;
        float v = acc[nt][r] + br1[col];
        v = v > 0.f ? v : 0.f;
        Ts[row][(((col >> 3) ^ (row & 7)) * 8) + (col & 7)] = f2bf(v);
      }
    }
  }

  for (int cg = 0; cg < 4; ++cg) {
    __syncthreads();
    {
      int col = tid & 63;
      int kb = (tid >> 6) * 16;
      unsigned pk[8];
#pragma unroll
      for (int i = 0; i < 8; ++i) {
        float lo = Wr2[(size_t)(kb + 2 * i) * 256 + cg * 64 + col];
        float hi = Wr2[(size_t)(kb + 2 * i + 1) * 256 + cg * 64 + col];
        pk[i] = (unsigned)f2bf(lo) | ((unsigned)f2bf(hi) << 16);
      }
      int g0 = kb >> 3;
      uint4 w0; w0.x = pk[0]; w0.y = pk[1]; w0.z = pk[2]; w0.w = pk[3];
      uint4 w1; w1.x = pk[4]; w1.y = pk[5]; w1.z = pk[6]; w1.w = pk[7];
      *(uint4*)&Ws[col][((g0) ^ (col & 7)) * 8] = w0;
      *(uint4*)&Ws[col][((g0 + 1) ^ (col & 7)) * 8] = w1;
    }
    __syncthreads();
    f32x4 acc[4] = {{0.f, 0.f, 0.f, 0.f}, {0.f, 0.f, 0.f, 0.f},
                    {0.f, 0.f, 0.f, 0.f}, {0.f, 0.f, 0.f, 0.f}};
#pragma unroll
    for (int ks = 0; ks < 2; ++ks) {
      int ga = ks * 4 + fg;
      bf16x8 af = *(const bf16x8*)&Ts[wm + fr][(ga ^ (fr & 7)) * 8];
#pragma unroll
      for (int nt = 0; nt < 4; ++nt) {
        bf16x8 bfr = *(const bf16x8*)&Ws[nt * 16 + fr][(ga ^ (fr & 7)) * 8];
        acc[nt] = __builtin_amdgcn_mfma_f32_16x16x32_bf16(af, bfr, acc[nt], 0, 0, 0);
      }
    }
#pragma unroll
    for (int nt = 0; nt < 4; ++nt) {
#pragma unroll
      for (int r = 0; r < 4; ++r) {
        int row = m0 + wm + fg * 4 + r;
        int col = cg * 64 + nt * 16 + fr;
        if (row < n) rec[(size_t)row * 256 + col] = acc[nt][r] + br2[col];
      }
    }
  }
}

// ---------------- GAT: fused segment softmax + bf16 gather (half-wave P3) ----------------
__device__ __forceinline__ float leaky(float v) { return v > 0.f ? v : 0.2f * v; }

__global__ __launch_bounds__(256) void k_gat(const unsigned short* __restrict__ xg16,
                                             const float* __restrict__ a_s,
                                             const float* __restrict__ a_d,
                                             const int* __restrict__ csr_src,
                                             const int* __restrict__ row_ptr,
                                             float* __restrict__ galpha,  // deg>128 fallback
                                             const float* __restrict__ bg,
                                             float* __restrict__ hg,      // d_out slice (8B-aligned)
                                             int n) {
  __shared__ float4 ew[4][128];
  const int wid = threadIdx.x >> 6;
  const int node = (blockIdx.x * 256 + threadIdx.x) >> 6;
  const int lane = threadIdx.x & 63;
  if (node >= n) return;
  const int beg = row_ptr[node], end = row_ptr[node + 1];
  const bool uselds = (end - beg) <= 128;
  float4 ad = ((const float4*)a_d)[node];

  float m0 = -1e30f, m1 = -1e30f, m2 = -1e30f, m3 = -1e30f;
  float4 e0, e1;
  const int i0 = beg + lane, i1 = beg + lane + 64;
  if (uselds) {
    if (i0 < end) {
      int s = csr_src[i0];
      float4 as = ((const float4*)a_s)[s];
      e0.x = leaky(as.x + ad.x); e0.y = leaky(as.y + ad.y);
      e0.z = leaky(as.z + ad.z); e0.w = leaky(as.w + ad.w);
      m0 = e0.x; m1 = e0.y; m2 = e0.z; m3 = e0.w;
    }
    if (i1 < end) {
      int s = csr_src[i1];
      float4 as = ((const float4*)a_s)[s];
      e1.x = leaky(as.x + ad.x); e1.y = leaky(as.y + ad.y);
      e1.z = leaky(as.z + ad.z); e1.w = leaky(as.w + ad.w);
      m0 = fmaxf(m0, e1.x); m1 = fmaxf(m1, e1.y);
      m2 = fmaxf(m2, e1.z); m3 = fmaxf(m3, e1.w);
    }
  } else {
    for (int i = i0; i < end; i += 64) {
      int s = csr_src[i];
      float4 as = ((const float4*)a_s)[s];
      float4 e;
      e.x = leaky(as.x + ad.x); e.y = leaky(as.y + ad.y);
      e.z = leaky(as.z + ad.z); e.w = leaky(as.w + ad.w);
      ((float4*)galpha)[i] = e;
      m0 = fmaxf(m0, e.x); m1 = fmaxf(m1, e.y);
      m2 = fmaxf(m2, e.z); m3 = fmaxf(m3, e.w);
    }
    __threadfence();
  }
#pragma unroll
  for (int o = 32; o > 0; o >>= 1) {
    m0 = fmaxf(m0, __shfl_xor(m0, o));
    m1 = fmaxf(m1, __shfl_xor(m1, o));
    m2 = fmaxf(m2, __shfl_xor(m2, o));
    m3 = fmaxf(m3, __shfl_xor(m3, o));
  }

  float s0 = 0.f, s1 = 0.f, s2 = 0.f, s3 = 0.f;
  if (uselds) {
    if (i0 < end) {
      float4 ex;
      ex.x = expf(e0.x - m0); ex.y = expf(e0.y - m1);
      ex.z = expf(e0.z - m2); ex.w = expf(e0.w - m3);
      ew[wid][i0 - beg] = ex;
      s0 += ex.x; s1 += ex.y; s2 += ex.z; s3 += ex.w;
    }
    if (i1 < end) {
      float4 ex;
      ex.x = expf(e1.x - m0); ex.y = expf(e1.y - m1);
      ex.z = expf(e1.z - m2); ex.w = expf(e1.w - m3);
      ew[wid][i1 - beg] = ex;
      s0 += ex.x; s1 += ex.y; s2 += ex.z; s3 += ex.w;
    }
  } else {
    for (int i = i0; i < end; i += 64) {
      float4 e = ((const float4*)galpha)[i];
      float4 ex;
      ex.x = expf(e.x - m0); ex.y = expf(e.y - m1);
      ex.z = expf(e.z - m2); ex.w = expf(e.w - m3);
      ((float4*)galpha)[i] = ex;
      s0 += ex.x; s1 += ex.y; s2 += ex.z; s3 += ex.w;
    }
    __threadfence();
  }
#pragma unroll
  for (int o = 32; o > 0; o >>= 1) {
    s0 += __shfl_xor(s0, o);
    s1 += __shfl_xor(s1, o);
    s2 += __shfl_xor(s2, o);
    s3 += __shfl_xor(s3, o);
  }
  float r0 = 0.25f / s0, r1 = 0.25f / s1, r2 = 0.25f / s2, r3 = 0.25f / s3;

  const int hl = lane & 31;
  const int hw = lane >> 5;
  const int head = hl >> 3;
  float a[8] = {}, b[8] = {};

#define GATHER8(ACC, S, AL)                                                     \
  {                                                                             \
    uint4 v = *(const uint4*)(xg16 + (size_t)(S) * 256 + hl * 8);               \
    ACC[0] = fmaf(bflo(v.x), AL, ACC[0]); ACC[1] = fmaf(bfhi(v.x), AL, ACC[1]); \
    ACC[2] = fmaf(bflo(v.y), AL, ACC[2]); ACC[3] = fmaf(bfhi(v.y), AL, ACC[3]); \
    ACC[4] = fmaf(bflo(v.z), AL, ACC[4]); ACC[5] = fmaf(bfhi(v.z), AL, ACC[5]); \
    ACC[6] = fmaf(bflo(v.w), AL, ACC[6]); ACC[7] = fmaf(bfhi(v.w), AL, ACC[7]); \
  }

#define P3_BODY(ALPHA_AT)                                  \
  {                                                        \
    int i = beg + hw;                                      \
    for (; i + 2 < end; i += 4) {                          \
      int sA = csr_src[i], sB = csr_src[i + 2];            \
      float alA = ALPHA_AT(i), alB = ALPHA_AT(i + 2);      \
      GATHER8(a, sA, alA)                                  \
      GATHER8(b, sB, alB)                                  \
    }                                                      \
    for (; i < end; i += 2) {                              \
      int s = csr_src[i];                                  \
      float al = ALPHA_AT(i);                              \
      GATHER8(a, s, al)                                    \
    }                                                      \
  }

  if (uselds) {
    const float* ap = (const float*)&ew[wid][0];
#define AL_LDS(idx) ap[((idx) - beg) * 4 + head]
    P3_BODY(AL_LDS)
#undef AL_LDS
  } else {
#define AL_GBL(idx) galpha[(size_t)(idx) * 4 + head]
    P3_BODY(AL_GBL)
#undef AL_GBL
  }
#undef P3_BODY
#undef GATHER8

  float rh = head == 0 ? r0 : head == 1 ? r1 : head == 2 ? r2 : r3;
  float t[8];
#pragma unroll
  for (int k = 0; k < 8; ++k) {
    t[k] = a[k] + b[k];
    t[k] += __shfl_xor(t[k], 32);
    t[k] *= rh;
    t[k] += __shfl_xor(t[k], 8);
    t[k] += __shfl_xor(t[k], 16);
  }
  if (lane < 8) {
    int f0 = lane * 8;
    float o0[8];
#pragma unroll
    for (int k = 0; k < 8; ++k) o0[k] = t[k] + bg[f0 + k];
    float2 p0; p0.x = o0[0]; p0.y = o0[1];
    float2 p1; p1.x = o0[2]; p1.y = o0[3];
    float2 p2; p2.x = o0[4]; p2.y = o0[5];
    float2 p3; p3.x = o0[6]; p3.y = o0[7];
    *(float2*)(hg + (size_t)node * HD + f0) = p0;
    *(float2*)(hg + (size_t)node * HD + f0 + 2) = p1;
    *(float2*)(hg + (size_t)node * HD + f0 + 4) = p2;
    *(float2*)(hg + (size_t)node * HD + f0 + 6) = p3;
  }
}

// tiny classifier head
__global__ __launch_bounds__(64) void k_cls(const float* __restrict__ gsum,
                                            const float* __restrict__ Wc1,
                                            const float* __restrict__ bc1,
                                            const float* __restrict__ Wc2,
                                            const float* __restrict__ bc2,
                                            float* __restrict__ out, int n) {
  __shared__ float hgl[64];
  __shared__ float t1[32];
  int t = threadIdx.x;
  hgl[t] = gsum[t] / (float)n;
  __syncthreads();
  if (t < 32) {
    float a = bc1[t];
#pragma unroll 16
    for (int f = 0; f < 64; ++f) a = fmaf(hgl[f], Wc1[f * 32 + t], a);
    t1[t] = a > 0.f ? a : 0.f;
  }
  __syncthreads();
  if (t < 2) {
    float a = bc2[t];
#pragma unroll
    for (int j = 0; j < 32; ++j) a = fmaf(t1[j], Wc2[j * 2 + t], a);
    out[t] = a;
  }
}

extern "C" void kernel_launch(void* const* d_in, const int* in_sizes, int n_in,
                              void* d_out, int out_size, void* d_ws, size_t ws_size,
                              hipStream_t stream) {
  const float* x = (const float*)d_in[0];
  const int* ei = (const int*)d_in[1];
  const float* W0 = (const float*)d_in[2];
  const float* b0 = (const float*)d_in[3];
  const float* W1 = (const float*)d_in[4];
  const float* b1 = (const float*)d_in[5];
  const float* W2 = (const float*)d_in[6];
  const float* b2 = (const float*)d_in[7];
  const float* Wg = (const float*)d_in[8];
  const float* att_src = (const float*)d_in[9];
  const float* att_dst = (const float*)d_in[10];
  const float* bg = (const float*)d_in[11];
  const float* Wc1 = (const float*)d_in[12];
  const float* bc1 = (const float*)d_in[13];
  const float* Wc2 = (const float*)d_in[14];
  const float* bc2 = (const float*)d_in[15];
  const float* Wr1 = (const float*)d_in[16];
  const float* br1 = (const float*)d_in[17];
  const float* Wr2 = (const float*)d_in[18];
  const float* br2 = (const float*)d_in[19];

  const int n = in_sizes[0] / DIN;  // 50000
  const int E = in_sizes[1] / 2;    // 800000
  const int nE = E + n;
  const int* src = ei;
  const int* dst = ei + E;

  // ---- workspace layout ----
  float* ws = (float*)d_ws;
  size_t off = 0;
  auto alloc = [&](size_t nelems) {
    float* p = ws + off;
    off += (nelems + 63) & ~(size_t)63;
    return p;
  };
  int* CNT = (int*)alloc(n);
  int* BSUM = (int*)alloc(256);
  int* ROWP = (int*)alloc(n + 1);
  int* CURS = (int*)alloc(n);
  int* CSRS = (int*)alloc(nE);
  float* DINV = alloc(n);
  unsigned short* XG16 = (unsigned short*)alloc((size_t)n * 128);  // bf16 xg [n,256]
  unsigned short* P16A = (unsigned short*)alloc((size_t)n * 32);   // bf16 [n,64] ping
  unsigned short* P16B = (unsigned short*)alloc((size_t)n * 32);   // bf16 [n,64] pong
  float* Hb = alloc((size_t)n * HD);                               // f32 h (resid chain)
  float* ASD = alloc((size_t)n * NHEAD);
  float* ADD = alloc((size_t)n * NHEAD);
  float* GALPHA = alloc((size_t)nE * NHEAD);                       // deg>128 fallback only
  float* GSUM = alloc(64);
  (void)ws_size;

  float* out = (float*)d_out;
  float* out_cls = out;                       // 2
  float* out_rec = out + 2;                   // n*256
  float* out_hg = out + 2 + (size_t)n * 256;  // n*64

  const int TB = 256;
  const int B = cdiv(n, TB);
  const int GM = cdiv(n, 64);

  // ---- CSR build ----
  hipMemsetAsync(CNT, 0, (size_t)n * sizeof(int), stream);
  k_count<<<cdiv(E, TB), TB, 0, stream>>>(dst, CNT, E);
  k_bsum<<<B, TB, 0, stream>>>(CNT, BSUM, n);
  k_rowptr<<<B, TB, 0, stream>>>(CNT, BSUM, ROWP, CURS, DINV, GSUM, n, nE, B);
  k_csrfill<<<cdiv(nE, TB), TB, 0, stream>>>(src, dst, CURS, CSRS, E, n);

  // ---- GCN stack (fused gather+GEMM layers) ----
  k_gmfma0<<<GM, TB, 0, stream>>>(x, W0, P16A, n);
  k_layer<0, 1, 0><<<GM, TB, 0, stream>>>(P16A, CSRS, ROWP, DINV, b0, nullptr, Hb,
                                          W1, P16B, nullptr, nullptr, nullptr, nullptr, n);
  k_layer<1, 1, 0><<<GM, TB, 0, stream>>>(P16B, CSRS, ROWP, DINV, b1, Hb, Hb,
                                          W2, P16A, nullptr, nullptr, nullptr, nullptr, n);
  k_layer<1, 0, 1><<<GM, TB, 0, stream>>>(P16A, CSRS, ROWP, DINV, b2, Hb, nullptr,
                                          Wg, XG16, att_src, att_dst, ASD, ADD, n);

  // ---- GAT ----
  k_gat<<<cdiv((long)n * 64, TB), TB, 0, stream>>>(XG16, ASD, ADD, CSRS, ROWP, GALPHA, bg,
                                                   out_hg, n);

  // ---- heads ----
  k_rec<<<GM, TB, 0, stream>>>(out_hg, Wr1, br1, Wr2, br2, GSUM, out_rec, n);
  k_cls<<<1, 64, 0, stream>>>(GSUM, Wc1, bc1, Wc2, bc2, out_cls, n);
}

// Round 13
// 352.934 us; speedup vs baseline: 1.1138x; 1.1138x over previous
//
#include <hip/hip_runtime.h>

#define DIN 256
#define HD 64
#define NHEAD 4

static inline int cdiv(long a, long b) { return (int)((a + b - 1) / b); }

typedef __attribute__((ext_vector_type(8))) short bf16x8;
typedef __attribute__((ext_vector_type(4))) float f32x4;

// ---------------- CSR build ----------------
__global__ __launch_bounds__(256) void k_count(const int* __restrict__ dst,
                                               int* __restrict__ cnt, int E) {
  int i = blockIdx.x * 256 + threadIdx.x;
  if (i < E) atomicAdd(&cnt[dst[i]], 1);
}

// block sums of (cnt+1)
__global__ __launch_bounds__(256) void k_bsum(const int* __restrict__ cnt,
                                              int* __restrict__ bsum, int n) {
  __shared__ int sd[256];
  int i = blockIdx.x * 256 + threadIdx.x;
  sd[threadIdx.x] = (i < n) ? cnt[i] + 1 : 0;
  __syncthreads();
  for (int o = 128; o > 0; o >>= 1) {
    if (threadIdx.x < o) sd[threadIdx.x] += sd[threadIdx.x + o];
    __syncthreads();
  }
  if (threadIdx.x == 0) bsum[blockIdx.x] = sd[0];
}

// rowptr (scans bsum inline) + cursor + dinv + GSUM zero
__global__ __launch_bounds__(256) void k_rowptr(const int* __restrict__ cnt,
                                                const int* __restrict__ bsum,
                                                int* __restrict__ row_ptr,
                                                int* __restrict__ cursor,
                                                float* __restrict__ dinv,
                                                float* __restrict__ gsum,
                                                int n, int total, int B) {
  __shared__ int sb[256];
  __shared__ int sd[256];
  int t = threadIdx.x;
  sb[t] = (t < B) ? bsum[t] : 0;
  __syncthreads();
  for (int o = 1; o < 256; o <<= 1) {
    int x = (t >= o) ? sb[t - o] : 0;
    __syncthreads();
    sb[t] += x;
    __syncthreads();
  }
  int boff = (blockIdx.x > 0) ? sb[blockIdx.x - 1] : 0;
  int i = blockIdx.x * 256 + t;
  int v = (i < n) ? cnt[i] + 1 : 0;
  sd[t] = v;
  __syncthreads();
  for (int o = 1; o < 256; o <<= 1) {
    int x = (t >= o) ? sd[t - o] : 0;
    __syncthreads();
    sd[t] += x;
    __syncthreads();
  }
  if (i < n) {
    int rp = boff + sd[t] - v;
    row_ptr[i] = rp;
    cursor[i] = rp;
    dinv[i] = rsqrtf((float)v);
  }
  if (i == n - 1) row_ptr[n] = total;
  if (blockIdx.x == 0 && t < 64) gsum[t] = 0.f;
}

__global__ __launch_bounds__(256) void k_csrfill(const int* __restrict__ src,
                                                 const int* __restrict__ dst,
                                                 int* __restrict__ cursor,
                                                 int* __restrict__ csr_src, int E, int n) {
  int e = blockIdx.x * 256 + threadIdx.x;
  if (e < E) {
    int pos = atomicAdd(&cursor[dst[e]], 1);
    csr_src[pos] = src[e];
  } else if (e < E + n) {
    int i = e - E;
    int pos = atomicAdd(&cursor[i], 1);
    csr_src[pos] = i;
  }
}

// ---------------- bf16 helpers ----------------
__device__ __forceinline__ unsigned short f2bf(float f) {  // RNE
  unsigned u = __float_as_uint(f);
  u += 0x7FFFu + ((u >> 16) & 1u);
  return (unsigned short)(u >> 16);
}
__device__ __forceinline__ float bflo(unsigned u) { return __uint_as_float(u << 16); }
__device__ __forceinline__ float bfhi(unsigned u) { return __uint_as_float(u & 0xFFFF0000u); }

// ---------------- MFMA GEMM: c16[n,KOUT](bf16) = A[n,KIN](f32) @ W[KIN,KOUT](f32) ----------------
// ATT=1 (KOUT=256): also emit a_s/a_d head-dots (blockIdx.y = head).
template <int KIN, int KOUT, int ATT>
__global__ __launch_bounds__(256, 4) void k_gmfma(const float* __restrict__ A,
                                                  const float* __restrict__ W,
                                                  unsigned short* __restrict__ c16, int n,
                                                  const float* __restrict__ attS,
                                                  const float* __restrict__ attD,
                                                  float* __restrict__ a_s,
                                                  float* __restrict__ a_d) {
  __shared__ unsigned short As[64][64];  // [row][k, granule-swizzled]
  __shared__ unsigned short Wt[64][64];  // [col][k, granule-swizzled]
  const int tid = threadIdx.x;
  const int m0 = blockIdx.x * 64;
  const int n0 = blockIdx.y * 64;
  const int lane = tid & 63;
  const int wid = tid >> 6;
  const int wm = wid * 16;
  const int fr = lane & 15;
  const int fg = lane >> 4;
  f32x4 acc[4] = {{0.f, 0.f, 0.f, 0.f},
                  {0.f, 0.f, 0.f, 0.f},
                  {0.f, 0.f, 0.f, 0.f},
                  {0.f, 0.f, 0.f, 0.f}};

  for (int k0 = 0; k0 < KIN; k0 += 64) {
    {
      int row = tid >> 3;  // 0..31
      int g = tid & 7;
#pragma unroll
      for (int q = 0; q < 2; ++q, row += 32) {
        int gr = m0 + row;
        gr = gr < n ? gr : n - 1;
        const float* ap = A + (size_t)gr * KIN + k0 + g * 8;
        float4 f0 = *(const float4*)ap;
        float4 f1 = *(const float4*)(ap + 4);
        uint4 pk;
        pk.x = (unsigned)f2bf(f0.x) | ((unsigned)f2bf(f0.y) << 16);
        pk.y = (unsigned)f2bf(f0.z) | ((unsigned)f2bf(f0.w) << 16);
        pk.z = (unsigned)f2bf(f1.x) | ((unsigned)f2bf(f1.y) << 16);
        pk.w = (unsigned)f2bf(f1.z) | ((unsigned)f2bf(f1.w) << 16);
        *(uint4*)&As[row][(g ^ (row & 7)) * 8] = pk;
      }
    }
    {
      int col = tid & 63;
      int kb = (tid >> 6) * 16;  // 0,16,32,48
      unsigned pk[8];
#pragma unroll
      for (int i = 0; i < 8; ++i) {
        float lo = W[(size_t)(k0 + kb + 2 * i) * KOUT + n0 + col];
        float hi = W[(size_t)(k0 + kb + 2 * i + 1) * KOUT + n0 + col];
        pk[i] = (unsigned)f2bf(lo) | ((unsigned)f2bf(hi) << 16);
      }
      int g0 = kb >> 3;
      uint4 w0; w0.x = pk[0]; w0.y = pk[1]; w0.z = pk[2]; w0.w = pk[3];
      uint4 w1; w1.x = pk[4]; w1.y = pk[5]; w1.z = pk[6]; w1.w = pk[7];
      *(uint4*)&Wt[col][((g0) ^ (col & 7)) * 8] = w0;
      *(uint4*)&Wt[col][((g0 + 1) ^ (col & 7)) * 8] = w1;
    }
    __syncthreads();
#pragma unroll
    for (int ks = 0; ks < 2; ++ks) {
      int ga = ks * 4 + fg;
      bf16x8 af = *(const bf16x8*)&As[wm + fr][(ga ^ (fr & 7)) * 8];
#pragma unroll
      for (int nt = 0; nt < 4; ++nt) {
        bf16x8 bfr = *(const bf16x8*)&Wt[nt * 16 + fr][(ga ^ (fr & 7)) * 8];
        acc[nt] = __builtin_amdgcn_mfma_f32_16x16x32_bf16(af, bfr, acc[nt], 0, 0, 0);
      }
    }
    __syncthreads();
  }

#pragma unroll
  for (int nt = 0; nt < 4; ++nt) {
#pragma unroll
    for (int r = 0; r < 4; ++r) {
      int row = m0 + wm + fg * 4 + r;
      if (row < n) c16[(size_t)row * KOUT + n0 + nt * 16 + fr] = f2bf(acc[nt][r]);
    }
  }
  if (ATT) {
    float attsv[4], attdv[4];
#pragma unroll
    for (int nt = 0; nt < 4; ++nt) {
      attsv[nt] = attS[n0 + nt * 16 + fr];
      attdv[nt] = attD[n0 + nt * 16 + fr];
    }
#pragma unroll
    for (int r = 0; r < 4; ++r) {
      float ps = acc[0][r] * attsv[0] + acc[1][r] * attsv[1] +
                 acc[2][r] * attsv[2] + acc[3][r] * attsv[3];
      float pd = acc[0][r] * attdv[0] + acc[1][r] * attdv[1] +
                 acc[2][r] * attdv[2] + acc[3][r] * attdv[3];
#pragma unroll
      for (int o = 1; o < 16; o <<= 1) {
        ps += __shfl_xor(ps, o);
        pd += __shfl_xor(pd, o);
      }
      int row = m0 + wm + fg * 4 + r;
      if (fr == 0 && row < n) {
        a_s[row * NHEAD + blockIdx.y] = ps;
        a_d[row * NHEAD + blockIdx.y] = pd;
      }
    }
  }
}

// ---------------- fused rec head: rec = relu(hg@Wr1+br1)@Wr2+br2, + gsum ----------------
__global__ __launch_bounds__(256, 4) void k_rec(const float* __restrict__ hg,
                                                const float* __restrict__ Wr1,
                                                const float* __restrict__ br1,
                                                const float* __restrict__ Wr2,
                                                const float* __restrict__ br2,
                                                float* __restrict__ gsum,
                                                float* __restrict__ rec,
                                                int n) {
  __shared__ unsigned short As[64][64];
  __shared__ unsigned short Ws[64][64];
  __shared__ unsigned short Ts[64][64];
  __shared__ float gs[64];
  const int tid = threadIdx.x;
  const int m0 = blockIdx.x * 64;
  const int lane = tid & 63;
  const int wid = tid >> 6;
  const int wm = wid * 16;
  const int fr = lane & 15, fg = lane >> 4;

  if (tid < 64) gs[tid] = 0.f;
  __syncthreads();

  {
    int row = tid >> 3, g = tid & 7;
#pragma unroll
    for (int q = 0; q < 2; ++q, row += 32) {
      int gr = m0 + row;
      bool valid = gr < n;
      int cr = valid ? gr : n - 1;
      const float* hp = hg + (size_t)cr * HD + g * 8;
      float2 f0 = *(const float2*)hp;
      float2 f1 = *(const float2*)(hp + 2);
      float2 f2 = *(const float2*)(hp + 4);
      float2 f3 = *(const float2*)(hp + 6);
      uint4 pk;
      pk.x = (unsigned)f2bf(f0.x) | ((unsigned)f2bf(f0.y) << 16);
      pk.y = (unsigned)f2bf(f1.x) | ((unsigned)f2bf(f1.y) << 16);
      pk.z = (unsigned)f2bf(f2.x) | ((unsigned)f2bf(f2.y) << 16);
      pk.w = (unsigned)f2bf(f3.x) | ((unsigned)f2bf(f3.y) << 16);
      *(uint4*)&As[row][(g ^ (row & 7)) * 8] = pk;
      if (valid) {
        atomicAdd(&gs[g * 8 + 0], f0.x); atomicAdd(&gs[g * 8 + 1], f0.y);
        atomicAdd(&gs[g * 8 + 2], f1.x); atomicAdd(&gs[g * 8 + 3], f1.y);
        atomicAdd(&gs[g * 8 + 4], f2.x); atomicAdd(&gs[g * 8 + 5], f2.y);
        atomicAdd(&gs[g * 8 + 6], f3.x); atomicAdd(&gs[g * 8 + 7], f3.y);
      }
    }
  }
  {
    int col = tid & 63;
    int kb = (tid >> 6) * 16;
    unsigned pk[8];
#pragma unroll
    for (int i = 0; i < 8; ++i) {
      float lo = Wr1[(size_t)(kb + 2 * i) * HD + col];
      float hi = Wr1[(size_t)(kb + 2 * i + 1) * HD + col];
      pk[i] = (unsigned)f2bf(lo) | ((unsigned)f2bf(hi) << 16);
    }
    int g0 = kb >> 3;
    uint4 w0; w0.x = pk[0]; w0.y = pk[1]; w0.z = pk[2]; w0.w = pk[3];
    uint4 w1; w1.x = pk[4]; w1.y = pk[5]; w1.z = pk[6]; w1.w = pk[7];
    *(uint4*)&Ws[col][((g0) ^ (col & 7)) * 8] = w0;
    *(uint4*)&Ws[col][((g0 + 1) ^ (col & 7)) * 8] = w1;
  }
  __syncthreads();
  if (tid < 64) atomicAdd(&gsum[tid], gs[tid]);

  {
    f32x4 acc[4] = {{0.f, 0.f, 0.f, 0.f}, {0.f, 0.f, 0.f, 0.f},
                    {0.f, 0.f, 0.f, 0.f}, {0.f, 0.f, 0.f, 0.f}};
#pragma unroll
    for (int ks = 0; ks < 2; ++ks) {
      int ga = ks * 4 + fg;
      bf16x8 af = *(const bf16x8*)&As[wm + fr][(ga ^ (fr & 7)) * 8];
#pragma unroll
      for (int nt = 0; nt < 4; ++nt) {
        bf16x8 bfr = *(const bf16x8*)&Ws[nt * 16 + fr][(ga ^ (fr & 7)) * 8];
        acc[nt] = __builtin_amdgcn_mfma_f32_16x16x32_bf16(af, bfr, acc[nt], 0, 0, 0);
      }
    }
#pragma unroll
    for (int nt = 0; nt < 4; ++nt) {
#pragma unroll
      for (int r = 0; r < 4; ++r) {
        int row = wm + fg * 4 + r;
        int col = nt * 16 + fr;
        float v = acc[nt][r] + br1[col];
        v = v > 0.f ? v : 0.f;
        Ts[row][(((col >> 3) ^ (row & 7)) * 8) + (col & 7)] = f2bf(v);
      }
    }
  }

  for (int cg = 0; cg < 4; ++cg) {
    __syncthreads();
    {
      int col = tid & 63;
      int kb = (tid >> 6) * 16;
      unsigned pk[8];
#pragma unroll
      for (int i = 0; i < 8; ++i) {
        float lo = Wr2[(size_t)(kb + 2 * i) * 256 + cg * 64 + col];
        float hi = Wr2[(size_t)(kb + 2 * i + 1) * 256 + cg * 64 + col];
        pk[i] = (unsigned)f2bf(lo) | ((unsigned)f2bf(hi) << 16);
      }
      int g0 = kb >> 3;
      uint4 w0; w0.x = pk[0]; w0.y = pk[1]; w0.z = pk[2]; w0.w = pk[3];
      uint4 w1; w1.x = pk[4]; w1.y = pk[5]; w1.z = pk[6]; w1.w = pk[7];
      *(uint4*)&Ws[col][((g0) ^ (col & 7)) * 8] = w0;
      *(uint4*)&Ws[col][((g0 + 1) ^ (col & 7)) * 8] = w1;
    }
    __syncthreads();
    f32x4 acc[4] = {{0.f, 0.f, 0.f, 0.f}, {0.f, 0.f, 0.f, 0.f},
                    {0.f, 0.f, 0.f, 0.f}, {0.f, 0.f, 0.f, 0.f}};
#pragma unroll
    for (int ks = 0; ks < 2; ++ks) {
      int ga = ks * 4 + fg;
      bf16x8 af = *(const bf16x8*)&Ts[wm + fr][(ga ^ (fr & 7)) * 8];
#pragma unroll
      for (int nt = 0; nt < 4; ++nt) {
        bf16x8 bfr = *(const bf16x8*)&Ws[nt * 16 + fr][(ga ^ (fr & 7)) * 8];
        acc[nt] = __builtin_amdgcn_mfma_f32_16x16x32_bf16(af, bfr, acc[nt], 0, 0, 0);
      }
    }
#pragma unroll
    for (int nt = 0; nt < 4; ++nt) {
#pragma unroll
      for (int r = 0; r < 4; ++r) {
        int row = m0 + wm + fg * 4 + r;
        int col = cg * 64 + nt * 16 + fr;
        if (row < n) rec[(size_t)row * 256 + col] = acc[nt][r] + br2[col];
      }
    }
  }
}

// ---------------- GCN aggregation, bf16 gather, eighth-wave per edge ----------------
__global__ __launch_bounds__(256) void k_agg16(const unsigned short* __restrict__ P16,
                                               const int* __restrict__ csr_src,
                                               const int* __restrict__ row_ptr,
                                               const float* __restrict__ dinv,
                                               const float* __restrict__ bias,
                                               const float* __restrict__ resid,
                                               float* __restrict__ out, int n) {
  int node = (blockIdx.x * 256 + threadIdx.x) >> 6;
  int lane = threadIdx.x & 63;
  if (node >= n) return;
  int beg = row_ptr[node], end = row_ptr[node + 1];
  int es = lane >> 3;        // edge slot 0..7
  int fo = (lane & 7) * 8;   // 8 feats per lane
  float a[8] = {};
  for (int i = beg + es; i < end; i += 8) {
    int s = csr_src[i];  // uniform within eighth
    float d = dinv[s];
    uint4 v = *(const uint4*)(P16 + (size_t)s * HD + fo);
    a[0] = fmaf(bflo(v.x), d, a[0]); a[1] = fmaf(bfhi(v.x), d, a[1]);
    a[2] = fmaf(bflo(v.y), d, a[2]); a[3] = fmaf(bfhi(v.y), d, a[3]);
    a[4] = fmaf(bflo(v.z), d, a[4]); a[5] = fmaf(bfhi(v.z), d, a[5]);
    a[6] = fmaf(bflo(v.w), d, a[6]); a[7] = fmaf(bfhi(v.w), d, a[7]);
  }
#pragma unroll
  for (int o = 8; o < 64; o <<= 1) {
#pragma unroll
    for (int k = 0; k < 8; ++k) a[k] += __shfl_xor(a[k], o);
  }
  if (lane < 8) {
    float dn = dinv[node];
    float4 b0 = *(const float4*)(bias + fo);
    float4 b1 = *(const float4*)(bias + fo + 4);
    float o0[8];
    o0[0] = a[0] * dn + b0.x; o0[1] = a[1] * dn + b0.y;
    o0[2] = a[2] * dn + b0.z; o0[3] = a[3] * dn + b0.w;
    o0[4] = a[4] * dn + b1.x; o0[5] = a[5] * dn + b1.y;
    o0[6] = a[6] * dn + b1.z; o0[7] = a[7] * dn + b1.w;
#pragma unroll
    for (int k = 0; k < 8; ++k) o0[k] = o0[k] > 0.f ? o0[k] : 0.f;
    if (resid) {
      float4 r0 = *(const float4*)(resid + (size_t)node * HD + fo);
      float4 r1 = *(const float4*)(resid + (size_t)node * HD + fo + 4);
      o0[0] += r0.x; o0[1] += r0.y; o0[2] += r0.z; o0[3] += r0.w;
      o0[4] += r1.x; o0[5] += r1.y; o0[6] += r1.z; o0[7] += r1.w;
    }
    float4 w0; w0.x = o0[0]; w0.y = o0[1]; w0.z = o0[2]; w0.w = o0[3];
    float4 w1; w1.x = o0[4]; w1.y = o0[5]; w1.z = o0[6]; w1.w = o0[7];
    *(float4*)(out + (size_t)node * HD + fo) = w0;
    *(float4*)(out + (size_t)node * HD + fo + 4) = w1;
  }
}

// ---------------- GAT: fused segment softmax + bf16 gather (half-wave P3, 4-deep) ----------------
__device__ __forceinline__ float leaky(float v) { return v > 0.f ? v : 0.2f * v; }

__global__ __launch_bounds__(256) void k_gat(const unsigned short* __restrict__ xg16,
                                             const float* __restrict__ a_s,
                                             const float* __restrict__ a_d,
                                             const int* __restrict__ csr_src,
                                             const int* __restrict__ row_ptr,
                                             float* __restrict__ galpha,  // deg>128 fallback
                                             const float* __restrict__ bg,
                                             float* __restrict__ hg,      // d_out slice (8B-aligned)
                                             int n) {
  __shared__ float4 ew[4][128];
  const int wid = threadIdx.x >> 6;
  const int node = (blockIdx.x * 256 + threadIdx.x) >> 6;
  const int lane = threadIdx.x & 63;
  if (node >= n) return;
  const int beg = row_ptr[node], end = row_ptr[node + 1];
  const bool uselds = (end - beg) <= 128;
  float4 ad = ((const float4*)a_d)[node];

  // P1: logits (registers if uselds), lane-local max
  float m0 = -1e30f, m1 = -1e30f, m2 = -1e30f, m3 = -1e30f;
  float4 e0, e1;
  const int i0 = beg + lane, i1 = beg + lane + 64;
  if (uselds) {
    if (i0 < end) {
      int s = csr_src[i0];
      float4 as = ((const float4*)a_s)[s];
      e0.x = leaky(as.x + ad.x); e0.y = leaky(as.y + ad.y);
      e0.z = leaky(as.z + ad.z); e0.w = leaky(as.w + ad.w);
      m0 = e0.x; m1 = e0.y; m2 = e0.z; m3 = e0.w;
    }
    if (i1 < end) {
      int s = csr_src[i1];
      float4 as = ((const float4*)a_s)[s];
      e1.x = leaky(as.x + ad.x); e1.y = leaky(as.y + ad.y);
      e1.z = leaky(as.z + ad.z); e1.w = leaky(as.w + ad.w);
      m0 = fmaxf(m0, e1.x); m1 = fmaxf(m1, e1.y);
      m2 = fmaxf(m2, e1.z); m3 = fmaxf(m3, e1.w);
    }
  } else {
    for (int i = i0; i < end; i += 64) {
      int s = csr_src[i];
      float4 as = ((const float4*)a_s)[s];
      float4 e;
      e.x = leaky(as.x + ad.x); e.y = leaky(as.y + ad.y);
      e.z = leaky(as.z + ad.z); e.w = leaky(as.w + ad.w);
      ((float4*)galpha)[i] = e;
      m0 = fmaxf(m0, e.x); m1 = fmaxf(m1, e.y);
      m2 = fmaxf(m2, e.z); m3 = fmaxf(m3, e.w);
    }
    __threadfence();
  }
#pragma unroll
  for (int o = 32; o > 0; o >>= 1) {
    m0 = fmaxf(m0, __shfl_xor(m0, o));
    m1 = fmaxf(m1, __shfl_xor(m1, o));
    m2 = fmaxf(m2, __shfl_xor(m2, o));
    m3 = fmaxf(m3, __shfl_xor(m3, o));
  }

  // P2: exp + store + lane-local sum
  float s0 = 0.f, s1 = 0.f, s2 = 0.f, s3 = 0.f;
  if (uselds) {
    if (i0 < end) {
      float4 ex;
      ex.x = expf(e0.x - m0); ex.y = expf(e0.y - m1);
      ex.z = expf(e0.z - m2); ex.w = expf(e0.w - m3);
      ew[wid][i0 - beg] = ex;
      s0 += ex.x; s1 += ex.y; s2 += ex.z; s3 += ex.w;
    }
    if (i1 < end) {
      float4 ex;
      ex.x = expf(e1.x - m0); ex.y = expf(e1.y - m1);
      ex.z = expf(e1.z - m2); ex.w = expf(e1.w - m3);
      ew[wid][i1 - beg] = ex;
      s0 += ex.x; s1 += ex.y; s2 += ex.z; s3 += ex.w;
    }
  } else {
    for (int i = i0; i < end; i += 64) {
      float4 e = ((const float4*)galpha)[i];
      float4 ex;
      ex.x = expf(e.x - m0); ex.y = expf(e.y - m1);
      ex.z = expf(e.z - m2); ex.w = expf(e.w - m3);
      ((float4*)galpha)[i] = ex;
      s0 += ex.x; s1 += ex.y; s2 += ex.z; s3 += ex.w;
    }
    __threadfence();
  }
#pragma unroll
  for (int o = 32; o > 0; o >>= 1) {
    s0 += __shfl_xor(s0, o);
    s1 += __shfl_xor(s1, o);
    s2 += __shfl_xor(s2, o);
    s3 += __shfl_xor(s3, o);
  }
  float r0 = 0.25f / s0, r1 = 0.25f / s1, r2 = 0.25f / s2, r3 = 0.25f / s3;

  // P3: half-wave per edge (32 lanes x uint4 = 512B row), 4 edges in flight.
  const int hl = lane & 31;
  const int hw = lane >> 5;
  const int head = hl >> 3;
  float a[8] = {}, b[8] = {}, c[8] = {}, d[8] = {};

#define GATHER8(ACC, S, AL)                                                     \
  {                                                                             \
    uint4 v = *(const uint4*)(xg16 + (size_t)(S) * 256 + hl * 8);               \
    ACC[0] = fmaf(bflo(v.x), AL, ACC[0]); ACC[1] = fmaf(bfhi(v.x), AL, ACC[1]); \
    ACC[2] = fmaf(bflo(v.y), AL, ACC[2]); ACC[3] = fmaf(bfhi(v.y), AL, ACC[3]); \
    ACC[4] = fmaf(bflo(v.z), AL, ACC[4]); ACC[5] = fmaf(bfhi(v.z), AL, ACC[5]); \
    ACC[6] = fmaf(bflo(v.w), AL, ACC[6]); ACC[7] = fmaf(bfhi(v.w), AL, ACC[7]); \
  }

#define P3_BODY(ALPHA_AT)                                                      \
  {                                                                            \
    int i = beg + hw;                                                          \
    for (; i + 6 < end; i += 8) {                                              \
      int sA = csr_src[i], sB = csr_src[i + 2];                                \
      int sC = csr_src[i + 4], sD = csr_src[i + 6];                            \
      float alA = ALPHA_AT(i), alB = ALPHA_AT(i + 2);                          \
      float alC = ALPHA_AT(i + 4), alD = ALPHA_AT(i + 6);                      \
      GATHER8(a, sA, alA)                                                      \
      GATHER8(b, sB, alB)                                                      \
      GATHER8(c, sC, alC)                                                      \
      GATHER8(d, sD, alD)                                                      \
    }                                                                          \
    for (; i < end; i += 2) {                                                  \
      int s = csr_src[i];                                                      \
      float al = ALPHA_AT(i);                                                  \
      GATHER8(a, s, al)                                                        \
    }                                                                          \
  }

  if (uselds) {
    const float* ap = (const float*)&ew[wid][0];
#define AL_LDS(idx) ap[((idx) - beg) * 4 + head]
    P3_BODY(AL_LDS)
#undef AL_LDS
  } else {
#define AL_GBL(idx) galpha[(size_t)(idx) * 4 + head]
    P3_BODY(AL_GBL)
#undef AL_GBL
  }
#undef P3_BODY
#undef GATHER8

  float rh = head == 0 ? r0 : head == 1 ? r1 : head == 2 ? r2 : r3;
  float t[8];
#pragma unroll
  for (int k = 0; k < 8; ++k) {
    t[k] = (a[k] + b[k]) + (c[k] + d[k]);
    t[k] += __shfl_xor(t[k], 32);  // combine half-waves
    t[k] *= rh;
    t[k] += __shfl_xor(t[k], 8);   // combine heads
    t[k] += __shfl_xor(t[k], 16);
  }
  if (lane < 8) {
    int f0 = lane * 8;
    float o0[8];
#pragma unroll
    for (int k = 0; k < 8; ++k) o0[k] = t[k] + bg[f0 + k];
    float2 p0; p0.x = o0[0]; p0.y = o0[1];
    float2 p1; p1.x = o0[2]; p1.y = o0[3];
    float2 p2; p2.x = o0[4]; p2.y = o0[5];
    float2 p3; p3.x = o0[6]; p3.y = o0[7];
    *(float2*)(hg + (size_t)node * HD + f0) = p0;
    *(float2*)(hg + (size_t)node * HD + f0 + 2) = p1;
    *(float2*)(hg + (size_t)node * HD + f0 + 4) = p2;
    *(float2*)(hg + (size_t)node * HD + f0 + 6) = p3;
  }
}

// tiny classifier head
__global__ __launch_bounds__(64) void k_cls(const float* __restrict__ gsum,
                                            const float* __restrict__ Wc1,
                                            const float* __restrict__ bc1,
                                            const float* __restrict__ Wc2,
                                            const float* __restrict__ bc2,
                                            float* __restrict__ out, int n) {
  __shared__ float hgl[64];
  __shared__ float t1[32];
  int t = threadIdx.x;
  hgl[t] = gsum[t] / (float)n;
  __syncthreads();
  if (t < 32) {
    float a = bc1[t];
#pragma unroll 16
    for (int f = 0; f < 64; ++f) a = fmaf(hgl[f], Wc1[f * 32 + t], a);
    t1[t] = a > 0.f ? a : 0.f;
  }
  __syncthreads();
  if (t < 2) {
    float a = bc2[t];
#pragma unroll
    for (int j = 0; j < 32; ++j) a = fmaf(t1[j], Wc2[j * 2 + t], a);
    out[t] = a;
  }
}

extern "C" void kernel_launch(void* const* d_in, const int* in_sizes, int n_in,
                              void* d_out, int out_size, void* d_ws, size_t ws_size,
                              hipStream_t stream) {
  const float* x = (const float*)d_in[0];
  const int* ei = (const int*)d_in[1];
  const float* W0 = (const float*)d_in[2];
  const float* b0 = (const float*)d_in[3];
  const float* W1 = (const float*)d_in[4];
  const float* b1 = (const float*)d_in[5];
  const float* W2 = (const float*)d_in[6];
  const float* b2 = (const float*)d_in[7];
  const float* Wg = (const float*)d_in[8];
  const float* att_src = (const float*)d_in[9];
  const float* att_dst = (const float*)d_in[10];
  const float* bg = (const float*)d_in[11];
  const float* Wc1 = (const float*)d_in[12];
  const float* bc1 = (const float*)d_in[13];
  const float* Wc2 = (const float*)d_in[14];
  const float* bc2 = (const float*)d_in[15];
  const float* Wr1 = (const float*)d_in[16];
  const float* br1 = (const float*)d_in[17];
  const float* Wr2 = (const float*)d_in[18];
  const float* br2 = (const float*)d_in[19];

  const int n = in_sizes[0] / DIN;  // 50000
  const int E = in_sizes[1] / 2;    // 800000
  const int nE = E + n;
  const int* src = ei;
  const int* dst = ei + E;

  // ---- workspace layout ----
  float* ws = (float*)d_ws;
  size_t off = 0;
  auto alloc = [&](size_t nelems) {
    float* p = ws + off;
    off += (nelems + 63) & ~(size_t)63;
    return p;
  };
  int* CNT = (int*)alloc(n);
  int* BSUM = (int*)alloc(256);
  int* ROWP = (int*)alloc(n + 1);
  int* CURS = (int*)alloc(n);
  int* CSRS = (int*)alloc(nE);
  float* DINV = alloc(n);
  unsigned short* XG16 = (unsigned short*)alloc((size_t)n * 128);  // bf16 xg [n,256]
  unsigned short* P16 = (unsigned short*)alloc((size_t)n * 32);    // bf16 P [n,64]
  float* Hb = alloc((size_t)n * HD);                               // f32 h (resid chain)
  float* ASD = alloc((size_t)n * NHEAD);
  float* ADD = alloc((size_t)n * NHEAD);
  float* GALPHA = alloc((size_t)nE * NHEAD);                       // deg>128 fallback only
  float* GSUM = alloc(64);
  (void)ws_size;

  float* out = (float*)d_out;
  float* out_cls = out;                       // 2
  float* out_rec = out + 2;                   // n*256
  float* out_hg = out + 2 + (size_t)n * 256;  // n*64

  const int TB = 256;
  const int B = cdiv(n, TB);
  const int GM = cdiv(n, 64);

  // ---- CSR build (by dst, self-loops as cnt+1) ----
  hipMemsetAsync(CNT, 0, (size_t)n * sizeof(int), stream);
  k_count<<<cdiv(E, TB), TB, 0, stream>>>(dst, CNT, E);
  k_bsum<<<B, TB, 0, stream>>>(CNT, BSUM, n);
  k_rowptr<<<B, TB, 0, stream>>>(CNT, BSUM, ROWP, CURS, DINV, GSUM, n, nE, B);
  k_csrfill<<<cdiv(nE, TB), TB, 0, stream>>>(src, dst, CURS, CSRS, E, n);

  // ---- GCN layers (MFMA GEMM -> bf16 message gather) ----
  k_gmfma<256, 64, 0><<<dim3(GM, 1), TB, 0, stream>>>(x, W0, P16, n,
                                                      nullptr, nullptr, nullptr, nullptr);
  k_agg16<<<cdiv((long)n * 64, TB), TB, 0, stream>>>(P16, CSRS, ROWP, DINV, b0, nullptr, Hb, n);

  k_gmfma<64, 64, 0><<<dim3(GM, 1), TB, 0, stream>>>(Hb, W1, P16, n,
                                                     nullptr, nullptr, nullptr, nullptr);
  k_agg16<<<cdiv((long)n * 64, TB), TB, 0, stream>>>(P16, CSRS, ROWP, DINV, b1, Hb, Hb, n);

  k_gmfma<64, 64, 0><<<dim3(GM, 1), TB, 0, stream>>>(Hb, W2, P16, n,
                                                     nullptr, nullptr, nullptr, nullptr);
  k_agg16<<<cdiv((long)n * 64, TB), TB, 0, stream>>>(P16, CSRS, ROWP, DINV, b2, Hb, Hb, n);

  // ---- GAT (att dots fused into MFMA epilogue) ----
  k_gmfma<64, 256, 1><<<dim3(GM, 4), TB, 0, stream>>>(Hb, Wg, XG16, n,
                                                      att_src, att_dst, ASD, ADD);
  k_gat<<<cdiv((long)n * 64, TB), TB, 0, stream>>>(XG16, ASD, ADD, CSRS, ROWP, GALPHA, bg,
                                                   out_hg, n);

  // ---- heads: fused rec (+gsum), then classifier ----
  k_rec<<<GM, TB, 0, stream>>>(out_hg, Wr1, br1, Wr2, br2, GSUM, out_rec, n);
  k_cls<<<1, 64, 0, stream>>>(GSUM, Wc1, bc1, Wc2, bc2, out_cls, n);
}

// Round 14
// 344.555 us; speedup vs baseline: 1.1409x; 1.0243x over previous
//
#include <hip/hip_runtime.h>

#define DIN 256
#define HD 64
#define NHEAD 4

static inline int cdiv(long a, long b) { return (int)((a + b - 1) / b); }

typedef __attribute__((ext_vector_type(8))) short bf16x8;
typedef __attribute__((ext_vector_type(4))) float f32x4;

// ---------------- CSR build ----------------
__global__ __launch_bounds__(256) void k_count(const int* __restrict__ dst,
                                               int* __restrict__ cnt, int E) {
  int i = blockIdx.x * 256 + threadIdx.x;
  if (i < E) atomicAdd(&cnt[dst[i]], 1);
}

// block sums of (cnt+1)
__global__ __launch_bounds__(256) void k_bsum(const int* __restrict__ cnt,
                                              int* __restrict__ bsum, int n) {
  __shared__ int sd[256];
  int i = blockIdx.x * 256 + threadIdx.x;
  sd[threadIdx.x] = (i < n) ? cnt[i] + 1 : 0;
  __syncthreads();
  for (int o = 128; o > 0; o >>= 1) {
    if (threadIdx.x < o) sd[threadIdx.x] += sd[threadIdx.x + o];
    __syncthreads();
  }
  if (threadIdx.x == 0) bsum[blockIdx.x] = sd[0];
}

// rowptr (scans bsum inline) + cursor + dinv + GSUM zero
__global__ __launch_bounds__(256) void k_rowptr(const int* __restrict__ cnt,
                                                const int* __restrict__ bsum,
                                                int* __restrict__ row_ptr,
                                                int* __restrict__ cursor,
                                                float* __restrict__ dinv,
                                                float* __restrict__ gsum,
                                                int n, int total, int B) {
  __shared__ int sb[256];
  __shared__ int sd[256];
  int t = threadIdx.x;
  sb[t] = (t < B) ? bsum[t] : 0;
  __syncthreads();
  for (int o = 1; o < 256; o <<= 1) {
    int x = (t >= o) ? sb[t - o] : 0;
    __syncthreads();
    sb[t] += x;
    __syncthreads();
  }
  int boff = (blockIdx.x > 0) ? sb[blockIdx.x - 1] : 0;
  int i = blockIdx.x * 256 + t;
  int v = (i < n) ? cnt[i] + 1 : 0;
  sd[t] = v;
  __syncthreads();
  for (int o = 1; o < 256; o <<= 1) {
    int x = (t >= o) ? sd[t - o] : 0;
    __syncthreads();
    sd[t] += x;
    __syncthreads();
  }
  if (i < n) {
    int rp = boff + sd[t] - v;
    row_ptr[i] = rp;
    cursor[i] = rp;
    dinv[i] = rsqrtf((float)v);
  }
  if (i == n - 1) row_ptr[n] = total;
  if (blockIdx.x == 0 && t < 64) gsum[t] = 0.f;
}

__global__ __launch_bounds__(256) void k_csrfill(const int* __restrict__ src,
                                                 const int* __restrict__ dst,
                                                 int* __restrict__ cursor,
                                                 int* __restrict__ csr_src, int E, int n) {
  int e = blockIdx.x * 256 + threadIdx.x;
  if (e < E) {
    int pos = atomicAdd(&cursor[dst[e]], 1);
    csr_src[pos] = src[e];
  } else if (e < E + n) {
    int i = e - E;
    int pos = atomicAdd(&cursor[i], 1);
    csr_src[pos] = i;
  }
}

// ---------------- bf16 helpers ----------------
__device__ __forceinline__ unsigned short f2bf(float f) {  // RNE
  unsigned u = __float_as_uint(f);
  u += 0x7FFFu + ((u >> 16) & 1u);
  return (unsigned short)(u >> 16);
}
__device__ __forceinline__ float bflo(unsigned u) { return __uint_as_float(u << 16); }
__device__ __forceinline__ float bfhi(unsigned u) { return __uint_as_float(u & 0xFFFF0000u); }

// ---------------- MFMA GEMM: c16[n,KOUT](bf16) = A[n,KIN](f32) @ W[KIN,KOUT](f32) ----------------
// ATT=1 (KOUT=256): also emit a_s/a_d head-dots (blockIdx.y = head).
template <int KIN, int KOUT, int ATT>
__global__ __launch_bounds__(256, 4) void k_gmfma(const float* __restrict__ A,
                                                  const float* __restrict__ W,
                                                  unsigned short* __restrict__ c16, int n,
                                                  const float* __restrict__ attS,
                                                  const float* __restrict__ attD,
                                                  float* __restrict__ a_s,
                                                  float* __restrict__ a_d) {
  __shared__ unsigned short As[64][64];  // [row][k, granule-swizzled]
  __shared__ unsigned short Wt[64][64];  // [col][k, granule-swizzled]
  const int tid = threadIdx.x;
  const int m0 = blockIdx.x * 64;
  const int n0 = blockIdx.y * 64;
  const int lane = tid & 63;
  const int wid = tid >> 6;
  const int wm = wid * 16;
  const int fr = lane & 15;
  const int fg = lane >> 4;
  f32x4 acc[4] = {{0.f, 0.f, 0.f, 0.f},
                  {0.f, 0.f, 0.f, 0.f},
                  {0.f, 0.f, 0.f, 0.f},
                  {0.f, 0.f, 0.f, 0.f}};

  for (int k0 = 0; k0 < KIN; k0 += 64) {
    {
      int row = tid >> 3;  // 0..31
      int g = tid & 7;
#pragma unroll
      for (int q = 0; q < 2; ++q, row += 32) {
        int gr = m0 + row;
        gr = gr < n ? gr : n - 1;
        const float* ap = A + (size_t)gr * KIN + k0 + g * 8;
        float4 f0 = *(const float4*)ap;
        float4 f1 = *(const float4*)(ap + 4);
        uint4 pk;
        pk.x = (unsigned)f2bf(f0.x) | ((unsigned)f2bf(f0.y) << 16);
        pk.y = (unsigned)f2bf(f0.z) | ((unsigned)f2bf(f0.w) << 16);
        pk.z = (unsigned)f2bf(f1.x) | ((unsigned)f2bf(f1.y) << 16);
        pk.w = (unsigned)f2bf(f1.z) | ((unsigned)f2bf(f1.w) << 16);
        *(uint4*)&As[row][(g ^ (row & 7)) * 8] = pk;
      }
    }
    {
      int col = tid & 63;
      int kb = (tid >> 6) * 16;  // 0,16,32,48
      unsigned pk[8];
#pragma unroll
      for (int i = 0; i < 8; ++i) {
        float lo = W[(size_t)(k0 + kb + 2 * i) * KOUT + n0 + col];
        float hi = W[(size_t)(k0 + kb + 2 * i + 1) * KOUT + n0 + col];
        pk[i] = (unsigned)f2bf(lo) | ((unsigned)f2bf(hi) << 16);
      }
      int g0 = kb >> 3;
      uint4 w0; w0.x = pk[0]; w0.y = pk[1]; w0.z = pk[2]; w0.w = pk[3];
      uint4 w1; w1.x = pk[4]; w1.y = pk[5]; w1.z = pk[6]; w1.w = pk[7];
      *(uint4*)&Wt[col][((g0) ^ (col & 7)) * 8] = w0;
      *(uint4*)&Wt[col][((g0 + 1) ^ (col & 7)) * 8] = w1;
    }
    __syncthreads();
#pragma unroll
    for (int ks = 0; ks < 2; ++ks) {
      int ga = ks * 4 + fg;
      bf16x8 af = *(const bf16x8*)&As[wm + fr][(ga ^ (fr & 7)) * 8];
#pragma unroll
      for (int nt = 0; nt < 4; ++nt) {
        bf16x8 bfr = *(const bf16x8*)&Wt[nt * 16 + fr][(ga ^ (fr & 7)) * 8];
        acc[nt] = __builtin_amdgcn_mfma_f32_16x16x32_bf16(af, bfr, acc[nt], 0, 0, 0);
      }
    }
    __syncthreads();
  }

#pragma unroll
  for (int nt = 0; nt < 4; ++nt) {
#pragma unroll
    for (int r = 0; r < 4; ++r) {
      int row = m0 + wm + fg * 4 + r;
      if (row < n) c16[(size_t)row * KOUT + n0 + nt * 16 + fr] = f2bf(acc[nt][r]);
    }
  }
  if (ATT) {
    float attsv[4], attdv[4];
#pragma unroll
    for (int nt = 0; nt < 4; ++nt) {
      attsv[nt] = attS[n0 + nt * 16 + fr];
      attdv[nt] = attD[n0 + nt * 16 + fr];
    }
#pragma unroll
    for (int r = 0; r < 4; ++r) {
      float ps = acc[0][r] * attsv[0] + acc[1][r] * attsv[1] +
                 acc[2][r] * attsv[2] + acc[3][r] * attsv[3];
      float pd = acc[0][r] * attdv[0] + acc[1][r] * attdv[1] +
                 acc[2][r] * attdv[2] + acc[3][r] * attdv[3];
#pragma unroll
      for (int o = 1; o < 16; o <<= 1) {
        ps += __shfl_xor(ps, o);
        pd += __shfl_xor(pd, o);
      }
      int row = m0 + wm + fg * 4 + r;
      if (fr == 0 && row < n) {
        a_s[row * NHEAD + blockIdx.y] = ps;
        a_d[row * NHEAD + blockIdx.y] = pd;
      }
    }
  }
}

// ---------------- fused rec head: rec = relu(hg@Wr1+br1)@Wr2+br2, + gsum ----------------
__global__ __launch_bounds__(256, 4) void k_rec(const float* __restrict__ hg,
                                                const float* __restrict__ Wr1,
                                                const float* __restrict__ br1,
                                                const float* __restrict__ Wr2,
                                                const float* __restrict__ br2,
                                                float* __restrict__ gsum,
                                                float* __restrict__ rec,
                                                int n) {
  __shared__ unsigned short As[64][64];
  __shared__ unsigned short Ws[64][64];
  __shared__ unsigned short Ts[64][64];
  __shared__ float gs[64];
  const int tid = threadIdx.x;
  const int m0 = blockIdx.x * 64;
  const int lane = tid & 63;
  const int wid = tid >> 6;
  const int wm = wid * 16;
  const int fr = lane & 15, fg = lane >> 4;

  if (tid < 64) gs[tid] = 0.f;
  __syncthreads();

  {
    int row = tid >> 3, g = tid & 7;
#pragma unroll
    for (int q = 0; q < 2; ++q, row += 32) {
      int gr = m0 + row;
      bool valid = gr < n;
      int cr = valid ? gr : n - 1;
      const float* hp = hg + (size_t)cr * HD + g * 8;
      float2 f0 = *(const float2*)hp;
      float2 f1 = *(const float2*)(hp + 2);
      float2 f2 = *(const float2*)(hp + 4);
      float2 f3 = *(const float2*)(hp + 6);
      uint4 pk;
      pk.x = (unsigned)f2bf(f0.x) | ((unsigned)f2bf(f0.y) << 16);
      pk.y = (unsigned)f2bf(f1.x) | ((unsigned)f2bf(f1.y) << 16);
      pk.z = (unsigned)f2bf(f2.x) | ((unsigned)f2bf(f2.y) << 16);
      pk.w = (unsigned)f2bf(f3.x) | ((unsigned)f2bf(f3.y) << 16);
      *(uint4*)&As[row][(g ^ (row & 7)) * 8] = pk;
      if (valid) {
        atomicAdd(&gs[g * 8 + 0], f0.x); atomicAdd(&gs[g * 8 + 1], f0.y);
        atomicAdd(&gs[g * 8 + 2], f1.x); atomicAdd(&gs[g * 8 + 3], f1.y);
        atomicAdd(&gs[g * 8 + 4], f2.x); atomicAdd(&gs[g * 8 + 5], f2.y);
        atomicAdd(&gs[g * 8 + 6], f3.x); atomicAdd(&gs[g * 8 + 7], f3.y);
      }
    }
  }
  {
    int col = tid & 63;
    int kb = (tid >> 6) * 16;
    unsigned pk[8];
#pragma unroll
    for (int i = 0; i < 8; ++i) {
      float lo = Wr1[(size_t)(kb + 2 * i) * HD + col];
      float hi = Wr1[(size_t)(kb + 2 * i + 1) * HD + col];
      pk[i] = (unsigned)f2bf(lo) | ((unsigned)f2bf(hi) << 16);
    }
    int g0 = kb >> 3;
    uint4 w0; w0.x = pk[0]; w0.y = pk[1]; w0.z = pk[2]; w0.w = pk[3];
    uint4 w1; w1.x = pk[4]; w1.y = pk[5]; w1.z = pk[6]; w1.w = pk[7];
    *(uint4*)&Ws[col][((g0) ^ (col & 7)) * 8] = w0;
    *(uint4*)&Ws[col][((g0 + 1) ^ (col & 7)) * 8] = w1;
  }
  __syncthreads();
  if (tid < 64) atomicAdd(&gsum[tid], gs[tid]);

  {
    f32x4 acc[4] = {{0.f, 0.f, 0.f, 0.f}, {0.f, 0.f, 0.f, 0.f},
                    {0.f, 0.f, 0.f, 0.f}, {0.f, 0.f, 0.f, 0.f}};
#pragma unroll
    for (int ks = 0; ks < 2; ++ks) {
      int ga = ks * 4 + fg;
      bf16x8 af = *(const bf16x8*)&As[wm + fr][(ga ^ (fr & 7)) * 8];
#pragma unroll
      for (int nt = 0; nt < 4; ++nt) {
        bf16x8 bfr = *(const bf16x8*)&Ws[nt * 16 + fr][(ga ^ (fr & 7)) * 8];
        acc[nt] = __builtin_amdgcn_mfma_f32_16x16x32_bf16(af, bfr, acc[nt], 0, 0, 0);
      }
    }
#pragma unroll
    for (int nt = 0; nt < 4; ++nt) {
#pragma unroll
      for (int r = 0; r < 4; ++r) {
        int row = wm + fg * 4 + r;
        int col = nt * 16 + fr;
        float v = acc[nt][r] + br1[col];
        v = v > 0.f ? v : 0.f;
        Ts[row][(((col >> 3) ^ (row & 7)) * 8) + (col & 7)] = f2bf(v);
      }
    }
  }

  for (int cg = 0; cg < 4; ++cg) {
    __syncthreads();
    {
      int col = tid & 63;
      int kb = (tid >> 6) * 16;
      unsigned pk[8];
#pragma unroll
      for (int i = 0; i < 8; ++i) {
        float lo = Wr2[(size_t)(kb + 2 * i) * 256 + cg * 64 + col];
        float hi = Wr2[(size_t)(kb + 2 * i + 1) * 256 + cg * 64 + col];
        pk[i] = (unsigned)f2bf(lo) | ((unsigned)f2bf(hi) << 16);
      }
      int g0 = kb >> 3;
      uint4 w0; w0.x = pk[0]; w0.y = pk[1]; w0.z = pk[2]; w0.w = pk[3];
      uint4 w1; w1.x = pk[4]; w1.y = pk[5]; w1.z = pk[6]; w1.w = pk[7];
      *(uint4*)&Ws[col][((g0) ^ (col & 7)) * 8] = w0;
      *(uint4*)&Ws[col][((g0 + 1) ^ (col & 7)) * 8] = w1;
    }
    __syncthreads();
    f32x4 acc[4] = {{0.f, 0.f, 0.f, 0.f}, {0.f, 0.f, 0.f, 0.f},
                    {0.f, 0.f, 0.f, 0.f}, {0.f, 0.f, 0.f, 0.f}};
#pragma unroll
    for (int ks = 0; ks < 2; ++ks) {
      int ga = ks * 4 + fg;
      bf16x8 af = *(const bf16x8*)&Ts[wm + fr][(ga ^ (fr & 7)) * 8];
#pragma unroll
      for (int nt = 0; nt < 4; ++nt) {
        bf16x8 bfr = *(const bf16x8*)&Ws[nt * 16 + fr][(ga ^ (fr & 7)) * 8];
        acc[nt] = __builtin_amdgcn_mfma_f32_16x16x32_bf16(af, bfr, acc[nt], 0, 0, 0);
      }
    }
#pragma unroll
    for (int nt = 0; nt < 4; ++nt) {
#pragma unroll
      for (int r = 0; r < 4; ++r) {
        int row = m0 + wm + fg * 4 + r;
        int col = cg * 64 + nt * 16 + fr;
        if (row < n) rec[(size_t)row * 256 + col] = acc[nt][r] + br2[col];
      }
    }
  }
}

// ---------------- GCN aggregation, bf16 gather, eighth-wave per edge ----------------
__global__ __launch_bounds__(256) void k_agg16(const unsigned short* __restrict__ P16,
                                               const int* __restrict__ csr_src,
                                               const int* __restrict__ row_ptr,
                                               const float* __restrict__ dinv,
                                               const float* __restrict__ bias,
                                               const float* __restrict__ resid,
                                               float* __restrict__ out, int n) {
  int node = (blockIdx.x * 256 + threadIdx.x) >> 6;
  int lane = threadIdx.x & 63;
  if (node >= n) return;
  int beg = row_ptr[node], end = row_ptr[node + 1];
  int es = lane >> 3;        // edge slot 0..7
  int fo = (lane & 7) * 8;   // 8 feats per lane
  float a[8] = {};
  for (int i = beg + es; i < end; i += 8) {
    int s = csr_src[i];  // uniform within eighth
    float d = dinv[s];
    uint4 v = *(const uint4*)(P16 + (size_t)s * HD + fo);
    a[0] = fmaf(bflo(v.x), d, a[0]); a[1] = fmaf(bfhi(v.x), d, a[1]);
    a[2] = fmaf(bflo(v.y), d, a[2]); a[3] = fmaf(bfhi(v.y), d, a[3]);
    a[4] = fmaf(bflo(v.z), d, a[4]); a[5] = fmaf(bfhi(v.z), d, a[5]);
    a[6] = fmaf(bflo(v.w), d, a[6]); a[7] = fmaf(bfhi(v.w), d, a[7]);
  }
#pragma unroll
  for (int o = 8; o < 64; o <<= 1) {
#pragma unroll
    for (int k = 0; k < 8; ++k) a[k] += __shfl_xor(a[k], o);
  }
  if (lane < 8) {
    float dn = dinv[node];
    float4 b0 = *(const float4*)(bias + fo);
    float4 b1 = *(const float4*)(bias + fo + 4);
    float o0[8];
    o0[0] = a[0] * dn + b0.x; o0[1] = a[1] * dn + b0.y;
    o0[2] = a[2] * dn + b0.z; o0[3] = a[3] * dn + b0.w;
    o0[4] = a[4] * dn + b1.x; o0[5] = a[5] * dn + b1.y;
    o0[6] = a[6] * dn + b1.z; o0[7] = a[7] * dn + b1.w;
#pragma unroll
    for (int k = 0; k < 8; ++k) o0[k] = o0[k] > 0.f ? o0[k] : 0.f;
    if (resid) {
      float4 r0 = *(const float4*)(resid + (size_t)node * HD + fo);
      float4 r1 = *(const float4*)(resid + (size_t)node * HD + fo + 4);
      o0[0] += r0.x; o0[1] += r0.y; o0[2] += r0.z; o0[3] += r0.w;
      o0[4] += r1.x; o0[5] += r1.y; o0[6] += r1.z; o0[7] += r1.w;
    }
    float4 w0; w0.x = o0[0]; w0.y = o0[1]; w0.z = o0[2]; w0.w = o0[3];
    float4 w1; w1.x = o0[4]; w1.y = o0[5]; w1.z = o0[6]; w1.w = o0[7];
    *(float4*)(out + (size_t)node * HD + fo) = w0;
    *(float4*)(out + (size_t)node * HD + fo + 4) = w1;
  }
}

// ---------------- GAT: fused segment softmax + bf16 gather (half-wave P3) ----------------
__device__ __forceinline__ float leaky(float v) { return v > 0.f ? v : 0.2f * v; }

__global__ __launch_bounds__(256) void k_gat(const unsigned short* __restrict__ xg16,
                                             const float* __restrict__ a_s,
                                             const float* __restrict__ a_d,
                                             const int* __restrict__ csr_src,
                                             const int* __restrict__ row_ptr,
                                             float* __restrict__ galpha,  // deg>128 fallback
                                             const float* __restrict__ bg,
                                             float* __restrict__ hg,      // d_out slice (8B-aligned)
                                             int n) {
  __shared__ float4 ew[4][128];
  const int wid = threadIdx.x >> 6;
  const int node = (blockIdx.x * 256 + threadIdx.x) >> 6;
  const int lane = threadIdx.x & 63;
  if (node >= n) return;
  const int beg = row_ptr[node], end = row_ptr[node + 1];
  const bool uselds = (end - beg) <= 128;
  float4 ad = ((const float4*)a_d)[node];

  float m0 = -1e30f, m1 = -1e30f, m2 = -1e30f, m3 = -1e30f;
  float4 e0, e1;
  const int i0 = beg + lane, i1 = beg + lane + 64;
  if (uselds) {
    if (i0 < end) {
      int s = csr_src[i0];
      float4 as = ((const float4*)a_s)[s];
      e0.x = leaky(as.x + ad.x); e0.y = leaky(as.y + ad.y);
      e0.z = leaky(as.z + ad.z); e0.w = leaky(as.w + ad.w);
      m0 = e0.x; m1 = e0.y; m2 = e0.z; m3 = e0.w;
    }
    if (i1 < end) {
      int s = csr_src[i1];
      float4 as = ((const float4*)a_s)[s];
      e1.x = leaky(as.x + ad.x); e1.y = leaky(as.y + ad.y);
      e1.z = leaky(as.z + ad.z); e1.w = leaky(as.w + ad.w);
      m0 = fmaxf(m0, e1.x); m1 = fmaxf(m1, e1.y);
      m2 = fmaxf(m2, e1.z); m3 = fmaxf(m3, e1.w);
    }
  } else {
    for (int i = i0; i < end; i += 64) {
      int s = csr_src[i];
      float4 as = ((const float4*)a_s)[s];
      float4 e;
      e.x = leaky(as.x + ad.x); e.y = leaky(as.y + ad.y);
      e.z = leaky(as.z + ad.z); e.w = leaky(as.w + ad.w);
      ((float4*)galpha)[i] = e;
      m0 = fmaxf(m0, e.x); m1 = fmaxf(m1, e.y);
      m2 = fmaxf(m2, e.z); m3 = fmaxf(m3, e.w);
    }
    __threadfence();
  }
#pragma unroll
  for (int o = 32; o > 0; o >>= 1) {
    m0 = fmaxf(m0, __shfl_xor(m0, o));
    m1 = fmaxf(m1, __shfl_xor(m1, o));
    m2 = fmaxf(m2, __shfl_xor(m2, o));
    m3 = fmaxf(m3, __shfl_xor(m3, o));
  }

  float s0 = 0.f, s1 = 0.f, s2 = 0.f, s3 = 0.f;
  if (uselds) {
    if (i0 < end) {
      float4 ex;
      ex.x = expf(e0.x - m0); ex.y = expf(e0.y - m1);
      ex.z = expf(e0.z - m2); ex.w = expf(e0.w - m3);
      ew[wid][i0 - beg] = ex;
      s0 += ex.x; s1 += ex.y; s2 += ex.z; s3 += ex.w;
    }
    if (i1 < end) {
      float4 ex;
      ex.x = expf(e1.x - m0); ex.y = expf(e1.y - m1);
      ex.z = expf(e1.z - m2); ex.w = expf(e1.w - m3);
      ew[wid][i1 - beg] = ex;
      s0 += ex.x; s1 += ex.y; s2 += ex.z; s3 += ex.w;
    }
  } else {
    for (int i = i0; i < end; i += 64) {
      float4 e = ((const float4*)galpha)[i];
      float4 ex;
      ex.x = expf(e.x - m0); ex.y = expf(e.y - m1);
      ex.z = expf(e.z - m2); ex.w = expf(e.w - m3);
      ((float4*)galpha)[i] = ex;
      s0 += ex.x; s1 += ex.y; s2 += ex.z; s3 += ex.w;
    }
    __threadfence();
  }
#pragma unroll
  for (int o = 32; o > 0; o >>= 1) {
    s0 += __shfl_xor(s0, o);
    s1 += __shfl_xor(s1, o);
    s2 += __shfl_xor(s2, o);
    s3 += __shfl_xor(s3, o);
  }
  float r0 = 0.25f / s0, r1 = 0.25f / s1, r2 = 0.25f / s2, r3 = 0.25f / s3;

  // P3: half-wave per edge (32 lanes x uint4 = 512B row), 2-unroll.
  const int hl = lane & 31;
  const int hw = lane >> 5;
  const int head = hl >> 3;
  float a[8] = {}, b[8] = {};

#define GATHER8(ACC, S, AL)                                                     \
  {                                                                             \
    uint4 v = *(const uint4*)(xg16 + (size_t)(S) * 256 + hl * 8);               \
    ACC[0] = fmaf(bflo(v.x), AL, ACC[0]); ACC[1] = fmaf(bfhi(v.x), AL, ACC[1]); \
    ACC[2] = fmaf(bflo(v.y), AL, ACC[2]); ACC[3] = fmaf(bfhi(v.y), AL, ACC[3]); \
    ACC[4] = fmaf(bflo(v.z), AL, ACC[4]); ACC[5] = fmaf(bfhi(v.z), AL, ACC[5]); \
    ACC[6] = fmaf(bflo(v.w), AL, ACC[6]); ACC[7] = fmaf(bfhi(v.w), AL, ACC[7]); \
  }

#define P3_BODY(ALPHA_AT)                                  \
  {                                                        \
    int i = beg + hw;                                      \
    for (; i + 2 < end; i += 4) {                          \
      int sA = csr_src[i], sB = csr_src[i + 2];            \
      float alA = ALPHA_AT(i), alB = ALPHA_AT(i + 2);      \
      GATHER8(a, sA, alA)                                  \
      GATHER8(b, sB, alB)                                  \
    }                                                      \
    for (; i < end; i += 2) {                              \
      int s = csr_src[i];                                  \
      float al = ALPHA_AT(i);                              \
      GATHER8(a, s, al)                                    \
    }                                                      \
  }

  if (uselds) {
    const float* ap = (const float*)&ew[wid][0];
#define AL_LDS(idx) ap[((idx) - beg) * 4 + head]
    P3_BODY(AL_LDS)
#undef AL_LDS
  } else {
#define AL_GBL(idx) galpha[(size_t)(idx) * 4 + head]
    P3_BODY(AL_GBL)
#undef AL_GBL
  }
#undef P3_BODY
#undef GATHER8

  float rh = head == 0 ? r0 : head == 1 ? r1 : head == 2 ? r2 : r3;
  float t[8];
#pragma unroll
  for (int k = 0; k < 8; ++k) {
    t[k] = a[k] + b[k];
    t[k] += __shfl_xor(t[k], 32);  // combine half-waves
    t[k] *= rh;
    t[k] += __shfl_xor(t[k], 8);   // combine heads
    t[k] += __shfl_xor(t[k], 16);
  }
  if (lane < 8) {
    int f0 = lane * 8;
    float o0[8];
#pragma unroll
    for (int k = 0; k < 8; ++k) o0[k] = t[k] + bg[f0 + k];
    float2 p0; p0.x = o0[0]; p0.y = o0[1];
    float2 p1; p1.x = o0[2]; p1.y = o0[3];
    float2 p2; p2.x = o0[4]; p2.y = o0[5];
    float2 p3; p3.x = o0[6]; p3.y = o0[7];
    *(float2*)(hg + (size_t)node * HD + f0) = p0;
    *(float2*)(hg + (size_t)node * HD + f0 + 2) = p1;
    *(float2*)(hg + (size_t)node * HD + f0 + 4) = p2;
    *(float2*)(hg + (size_t)node * HD + f0 + 6) = p3;
  }
}

// tiny classifier head
__global__ __launch_bounds__(64) void k_cls(const float* __restrict__ gsum,
                                            const float* __restrict__ Wc1,
                                            const float* __restrict__ bc1,
                                            const float* __restrict__ Wc2,
                                            const float* __restrict__ bc2,
                                            float* __restrict__ out, int n) {
  __shared__ float hgl[64];
  __shared__ float t1[32];
  int t = threadIdx.x;
  hgl[t] = gsum[t] / (float)n;
  __syncthreads();
  if (t < 32) {
    float a = bc1[t];
#pragma unroll 16
    for (int f = 0; f < 64; ++f) a = fmaf(hgl[f], Wc1[f * 32 + t], a);
    t1[t] = a > 0.f ? a : 0.f;
  }
  __syncthreads();
  if (t < 2) {
    float a = bc2[t];
#pragma unroll
    for (int j = 0; j < 32; ++j) a = fmaf(t1[j], Wc2[j * 2 + t], a);
    out[t] = a;
  }
}

extern "C" void kernel_launch(void* const* d_in, const int* in_sizes, int n_in,
                              void* d_out, int out_size, void* d_ws, size_t ws_size,
                              hipStream_t stream) {
  const float* x = (const float*)d_in[0];
  const int* ei = (const int*)d_in[1];
  const float* W0 = (const float*)d_in[2];
  const float* b0 = (const float*)d_in[3];
  const float* W1 = (const float*)d_in[4];
  const float* b1 = (const float*)d_in[5];
  const float* W2 = (const float*)d_in[6];
  const float* b2 = (const float*)d_in[7];
  const float* Wg = (const float*)d_in[8];
  const float* att_src = (const float*)d_in[9];
  const float* att_dst = (const float*)d_in[10];
  const float* bg = (const float*)d_in[11];
  const float* Wc1 = (const float*)d_in[12];
  const float* bc1 = (const float*)d_in[13];
  const float* Wc2 = (const float*)d_in[14];
  const float* bc2 = (const float*)d_in[15];
  const float* Wr1 = (const float*)d_in[16];
  const float* br1 = (const float*)d_in[17];
  const float* Wr2 = (const float*)d_in[18];
  const float* br2 = (const float*)d_in[19];

  const int n = in_sizes[0] / DIN;  // 50000
  const int E = in_sizes[1] / 2;    // 800000
  const int nE = E + n;
  const int* src = ei;
  const int* dst = ei + E;

  // ---- workspace layout ----
  float* ws = (float*)d_ws;
  size_t off = 0;
  auto alloc = [&](size_t nelems) {
    float* p = ws + off;
    off += (nelems + 63) & ~(size_t)63;
    return p;
  };
  int* CNT = (int*)alloc(n);
  int* BSUM = (int*)alloc(256);
  int* ROWP = (int*)alloc(n + 1);
  int* CURS = (int*)alloc(n);
  int* CSRS = (int*)alloc(nE);
  float* DINV = alloc(n);
  unsigned short* XG16 = (unsigned short*)alloc((size_t)n * 128);  // bf16 xg [n,256]
  unsigned short* P16 = (unsigned short*)alloc((size_t)n * 32);    // bf16 P [n,64]
  float* Hb = alloc((size_t)n * HD);                               // f32 h (resid chain)
  float* ASD = alloc((size_t)n * NHEAD);
  float* ADD = alloc((size_t)n * NHEAD);
  float* GALPHA = alloc((size_t)nE * NHEAD);                       // deg>128 fallback only
  float* GSUM = alloc(64);
  (void)ws_size;

  float* out = (float*)d_out;
  float* out_cls = out;                       // 2
  float* out_rec = out + 2;                   // n*256
  float* out_hg = out + 2 + (size_t)n * 256;  // n*64

  const int TB = 256;
  const int B = cdiv(n, TB);
  const int GM = cdiv(n, 64);

  // ---- CSR build (by dst, self-loops as cnt+1) ----
  hipMemsetAsync(CNT, 0, (size_t)n * sizeof(int), stream);
  k_count<<<cdiv(E, TB), TB, 0, stream>>>(dst, CNT, E);
  k_bsum<<<B, TB, 0, stream>>>(CNT, BSUM, n);
  k_rowptr<<<B, TB, 0, stream>>>(CNT, BSUM, ROWP, CURS, DINV, GSUM, n, nE, B);
  k_csrfill<<<cdiv(nE, TB), TB, 0, stream>>>(src, dst, CURS, CSRS, E, n);

  // ---- GCN layers (MFMA GEMM -> bf16 message gather) ----
  k_gmfma<256, 64, 0><<<dim3(GM, 1), TB, 0, stream>>>(x, W0, P16, n,
                                                      nullptr, nullptr, nullptr, nullptr);
  k_agg16<<<cdiv((long)n * 64, TB), TB, 0, stream>>>(P16, CSRS, ROWP, DINV, b0, nullptr, Hb, n);

  k_gmfma<64, 64, 0><<<dim3(GM, 1), TB, 0, stream>>>(Hb, W1, P16, n,
                                                     nullptr, nullptr, nullptr, nullptr);
  k_agg16<<<cdiv((long)n * 64, TB), TB, 0, stream>>>(P16, CSRS, ROWP, DINV, b1, Hb, Hb, n);

  k_gmfma<64, 64, 0><<<dim3(GM, 1), TB, 0, stream>>>(Hb, W2, P16, n,
                                                     nullptr, nullptr, nullptr, nullptr);
  k_agg16<<<cdiv((long)n * 64, TB), TB, 0, stream>>>(P16, CSRS, ROWP, DINV, b2, Hb, Hb, n);

  // ---- GAT (att dots fused into MFMA epilogue) ----
  k_gmfma<64, 256, 1><<<dim3(GM, 4), TB, 0, stream>>>(Hb, Wg, XG16, n,
                                                      att_src, att_dst, ASD, ADD);
  k_gat<<<cdiv((long)n * 64, TB), TB, 0, stream>>>(XG16, ASD, ADD, CSRS, ROWP, GALPHA, bg,
                                                   out_hg, n);

  // ---- heads: fused rec (+gsum), then classifier ----
  k_rec<<<GM, TB, 0, stream>>>(out_hg, Wr1, br1, Wr2, br2, GSUM, out_rec, n);
  k_cls<<<1, 64, 0, stream>>>(GSUM, Wc1, bc1, Wc2, bc2, out_cls, n);
}